// Round 7
// baseline (250.748 us; speedup 1.0000x reference)
//
#include <hip/hip_runtime.h>
#include <math.h>

// Problem constants
#define NRAYS        32768
#define MARCH_ITERS  64
#define EPS_         1e-4f
#define STEP_        ((1.0f + 1.0f/64.0f) / 64.0f)   // exact in fp32

typedef __attribute__((ext_vector_type(8)))  short    short8;   // 8 bf16
typedef __attribute__((ext_vector_type(4)))  float    float4v;  // C/D frag
typedef __attribute__((ext_vector_type(4)))  unsigned uint4v;

__device__ __forceinline__ short8 mk_frag(unsigned p0, unsigned p1,
                                          unsigned p2, unsigned p3) {
    uint4v v = {p0, p1, p2, p3};
    return __builtin_bit_cast(short8, v);
}

// One v_perm_b32: low16 = trunc-bf16(a), high16 = trunc-bf16(b).
__device__ __forceinline__ unsigned packbf(unsigned a, unsigned b) {
    return __builtin_amdgcn_perm(b, a, 0x07060302u);
}

// Exact 3-way truncation split: x == hi + mid + lo bit-exactly in fp32.
struct Split3 { unsigned h, m, l; };
__device__ __forceinline__ Split3 split3(float x) {
    unsigned xu = __float_as_uint(x);
    float xh = __uint_as_float(xu & 0xFFFF0000u);
    float r  = x - xh;                        // exact
    unsigned ru = __float_as_uint(r);
    float xm = __uint_as_float(ru & 0xFFFF0000u);
    float r2 = r - xm;                        // exact, fits bf16
    return { xu, ru, __float_as_uint(r2) };
}

// 2-way split (hi + mid, drops O(2^-18) tail) — for the non-chaotic tput scan.
struct Split2 { unsigned h, r; };
__device__ __forceinline__ Split2 split2(float x) {
    unsigned xu = __float_as_uint(x);
    float xh = __uint_as_float(xu & 0xFFFF0000u);
    float rr = x - xh;                        // exact residual
    return { xu, __float_as_uint(rr) };
}

// One wave = 16 rays (ray = col everywhere). mfma_f32_16x16x32_bf16 layouts:
//   A[row=lane&15][k=(lane>>4)*8+j]   B[k=(lane>>4)*8+j][col=lane&15]
//   C/D: col=lane&15, row=(lane>>4)*4+reg
// L1 hidden assignment H(t,q,r) = 32*(t>>1) + 8q + 4*(t&1) + r makes the
// C1->B2 handoff purely in-lane (verified R6). Even blocks: exact 6-product
// march (chaotic, needs fp32-exact). Odd blocks: cheap 4-product tput scan
// (independent evals, error ~1e-4 vs 1.1e-2 threshold).
__global__ __launch_bounds__(256, 2) void sdf_tr3_k(
    const float* __restrict__ rays,
    const float* __restrict__ W0,  const float* __restrict__ b0,
    const float* __restrict__ W1,  const float* __restrict__ b1,
    const float* __restrict__ W2,  const float* __restrict__ b2,
    const float* __restrict__ Wr0, const float* __restrict__ br0,
    const float* __restrict__ Wr1, const float* __restrict__ br1,
    float* __restrict__ out)
{
    const int lane   = threadIdx.x & 63;
    const int waveId = threadIdx.x >> 6;
    const int quad   = lane >> 4;
    const int m      = lane & 15;
    const int kind   = blockIdx.x & 1;                 // 0=march, 1=tput
    const int rayBase = ((blockIdx.x >> 1) * 4 + waveId) * 16;

    // ---- per-lane ray (ray = rayBase + m, replicated over quads) ----
    const float* rp = rays + (rayBase + m) * 6;
    const float ox = rp[0], oy = rp[1], oz = rp[2];
    const float dx = rp[3], dy = rp[4], dz = rp[5];

    // ---- A2: W1^T splits in A-layout; [0]=hi,[1]=mid,[2]=lo ----
    // A2[s][h][t]: row j2 = 16t+m, k = 32h + 8*quad + jj (R3/R6-verified)
    short8 A2[3][2][4];
    #pragma unroll
    for (int h = 0; h < 2; ++h)
        #pragma unroll
        for (int t = 0; t < 4; ++t) {
            unsigned ph[4], pm[4], pl[4];
            #pragma unroll
            for (int jp = 0; jp < 4; ++jp) {
                int k0 = 32 * h + quad * 8 + 2 * jp;
                int j2 = 16 * t + m;
                Split3 a = split3(W1[k0 * 64 + j2]);
                Split3 b = split3(W1[(k0 + 1) * 64 + j2]);
                ph[jp] = packbf(a.h, b.h);
                pm[jp] = packbf(a.m, b.m);
                pl[jp] = packbf(a.l, b.l);
            }
            A2[0][h][t] = mk_frag(ph[0], ph[1], ph[2], ph[3]);
            A2[1][h][t] = mk_frag(pm[0], pm[1], pm[2], pm[3]);
            A2[2][h][t] = mk_frag(pl[0], pl[1], pl[2], pl[3]);
        }

    // ---- b1 (folded into C2 init) and W2, per-lane rows j2 = 16t+4q+r ----
    float4v b1v[4], w2v[4];
    #pragma unroll
    for (int t = 0; t < 4; ++t) {
        int base = 16 * t + 4 * quad;
        b1v[t] = (float4v){b1[base], b1[base + 1], b1[base + 2], b1[base + 3]};
        w2v[t] = (float4v){W2[base], W2[base + 1], W2[base + 2], W2[base + 3]};
    }
    const float b2s = b2[0];

    if (kind == 0) {
        // =================== MARCH: exact 6-product eval ===================
        // A1: W0^T 3-splits + b0 in A-layout K-slots (21 slots), R6-verified.
        short8 A1[4];
        #pragma unroll
        for (int t = 0; t < 4; ++t) {
            int j = 32 * (t >> 1) + 8 * (m >> 2) + 4 * (t & 1) + (m & 3);
            Split3 wx = split3(W0[j]);
            Split3 wy = split3(W0[64 + j]);
            Split3 wz = split3(W0[128 + j]);
            Split3 bb = split3(b0[j]);
            unsigned a0, a1, a2, a3;
            if      (quad == 0) { a0 = packbf(wx.h, wx.m); a1 = packbf(wx.l, wx.h);
                                  a2 = packbf(wx.m, wx.h); a3 = packbf(wy.h, wy.m); }
            else if (quad == 1) { a0 = packbf(wy.l, wy.h); a1 = packbf(wy.m, wy.h);
                                  a2 = packbf(wz.h, wz.m); a3 = packbf(wz.l, wz.h); }
            else if (quad == 2) { a0 = packbf(wz.m, wz.h); a1 = packbf(bb.h, bb.m);
                                  a2 = packbf(bb.l, 0u);   a3 = 0u; }
            else                { a0 = a1 = a2 = a3 = 0u; }
            A1[t] = mk_frag(a0, a1, a2, a3);
        }

        // L2 product order (sW, sH), small first: (m,m)(l,h)(h,l)(m,h)(h,m)(h,h)
        const int pw_[6] = {1, 2, 0, 1, 0, 0};
        const int ph_[6] = {1, 0, 2, 0, 1, 0};

        auto evalExact = [&](float px, float py, float pz) -> float {
            Split3 sx = split3(px), sy = split3(py), sz = split3(pz);
            unsigned d0, d1, d2, d3;
            if      (quad == 0) { d0 = packbf(sx.h, sx.h); d1 = packbf(sx.h, sx.m);
                                  d2 = packbf(sx.m, sx.l); d3 = packbf(sy.h, sy.h); }
            else if (quad == 1) { d0 = packbf(sy.h, sy.m); d1 = packbf(sy.m, sy.l);
                                  d2 = packbf(sz.h, sz.h); d3 = packbf(sz.h, sz.m); }
            else if (quad == 2) { d0 = packbf(sz.m, sz.l); d1 = 0x3F803F80u;
                                  d2 = 0x00003F80u;        d3 = 0u; }
            else                { d0 = d1 = d2 = d3 = 0u; }
            short8 B1 = mk_frag(d0, d1, d2, d3);

            const float4v z4 = {0.f, 0.f, 0.f, 0.f};
            float4v C1[4];
            #pragma unroll
            for (int t = 0; t < 4; ++t)
                C1[t] = __builtin_amdgcn_mfma_f32_16x16x32_bf16(A1[t], B1, z4, 0, 0, 0);

            unsigned P[3][4][2];
            #pragma unroll
            for (int t = 0; t < 4; ++t) {
                Split3 s0 = split3(fmaxf(C1[t][0], 0.f));
                Split3 s1 = split3(fmaxf(C1[t][1], 0.f));
                Split3 s2 = split3(fmaxf(C1[t][2], 0.f));
                Split3 s3 = split3(fmaxf(C1[t][3], 0.f));
                P[0][t][0] = packbf(s0.h, s1.h); P[0][t][1] = packbf(s2.h, s3.h);
                P[1][t][0] = packbf(s0.m, s1.m); P[1][t][1] = packbf(s2.m, s3.m);
                P[2][t][0] = packbf(s0.l, s1.l); P[2][t][1] = packbf(s2.l, s3.l);
            }
            short8 B2[3][2];
            #pragma unroll
            for (int s = 0; s < 3; ++s)
                #pragma unroll
                for (int h = 0; h < 2; ++h)
                    B2[s][h] = mk_frag(P[s][2 * h][0],     P[s][2 * h][1],
                                       P[s][2 * h + 1][0], P[s][2 * h + 1][1]);

            float4v C2[4];
            #pragma unroll
            for (int t = 0; t < 4; ++t) C2[t] = b1v[t];
            #pragma unroll
            for (int p = 0; p < 6; ++p)
                #pragma unroll
                for (int h = 0; h < 2; ++h)
                    #pragma unroll
                    for (int t = 0; t < 4; ++t)
                        C2[t] = __builtin_amdgcn_mfma_f32_16x16x32_bf16(
                            A2[pw_[p]][h][t], B2[ph_[p]][h], C2[t], 0, 0, 0);

            float q0 = 0.f, q1 = 0.f, q2 = 0.f, q3 = 0.f;
            #pragma unroll
            for (int t = 0; t < 4; ++t) {
                q0 = fmaf(fmaxf(C2[t][0], 0.f), w2v[t][0], q0);
                q1 = fmaf(fmaxf(C2[t][1], 0.f), w2v[t][1], q1);
                q2 = fmaf(fmaxf(C2[t][2], 0.f), w2v[t][2], q2);
                q3 = fmaf(fmaxf(C2[t][3], 0.f), w2v[t][3], q3);
            }
            float part = (q0 + q1) + (q2 + q3);
            part += __shfl_xor(part, 16, 64);
            part += __shfl_xor(part, 32, 64);
            return b2s + part;                       // d at every lane
        };

        bool  hit = false;
        float cd  = 0.f;
        #pragma unroll 1
        for (int it = 0; it < MARCH_ITERS; ++it) {
            float d = evalExact(fmaf(dx, cd, ox), fmaf(dy, cd, oy), fmaf(dz, cd, oz));
            bool c = (d < EPS_) && (cd >= 0.f) && (cd <= 1.f);
            hit = hit || c;
            if (!hit) cd += d;
            if (__all(hit)) break;               // all 16 rays frozen
        }

        // ---- reflection net: quad q handles hidden j in [16q, 16q+16) ----
        const float px = fmaf(dx, cd, ox), py = fmaf(dy, cd, oy), pz = fmaf(dz, cd, oz);
        float r0 = 0.f, r1 = 0.f, r2 = 0.f;
        #pragma unroll 4
        for (int jj = 0; jj < 16; ++jj) {
            int j = quad * 16 + jj;
            float a = fmaf(px, Wr0[j],
                      fmaf(py, Wr0[64 + j],
                      fmaf(pz, Wr0[128 + j],
                      fmaf(dx, Wr0[192 + j],
                      fmaf(dy, Wr0[256 + j],
                      fmaf(dz, Wr0[320 + j], br0[j]))))));
            a = fmaxf(a, 0.f);
            r0 = fmaf(a, Wr1[j * 3 + 0], r0);
            r1 = fmaf(a, Wr1[j * 3 + 1], r1);
            r2 = fmaf(a, Wr1[j * 3 + 2], r2);
        }
        r0 += __shfl_xor(r0, 16, 64); r0 += __shfl_xor(r0, 32, 64);
        r1 += __shfl_xor(r1, 16, 64); r1 += __shfl_xor(r1, 32, 64);
        r2 += __shfl_xor(r2, 16, 64); r2 += __shfl_xor(r2, 32, 64);
        r0 = 1.f / (1.f + expf(-(r0 + br1[0])));
        r1 = 1.f / (1.f + expf(-(r1 + br1[1])));
        r2 = 1.f / (1.f + expf(-(r2 + br1[2])));
        if (!hit) { r0 = 0.f; r1 = 0.f; r2 = 0.f; }
        if (lane < 16) {
            float* op = out + (rayBase + lane) * 4;
            op[0] = r0; op[1] = r1; op[2] = r2;
        }
    } else {
        // =================== TPUT: cheap 4-product eval ===================
        // L1 K-slots (14 used): per coord [WH,WM,WH,WM] x B [pH,pH,pM,pM];
        // bias at slots 12,13 with B-side ones. Dropped terms O(2^-18).
        short8 A1c[4];
        #pragma unroll
        for (int t = 0; t < 4; ++t) {
            int j = 32 * (t >> 1) + 8 * (m >> 2) + 4 * (t & 1) + (m & 3);
            Split2 wx = split2(W0[j]);
            Split2 wy = split2(W0[64 + j]);
            Split2 wz = split2(W0[128 + j]);
            Split2 bb = split2(b0[j]);
            unsigned a0, a1, a2, a3;
            if      (quad == 0) { a0 = packbf(wx.h, wx.r); a1 = a0;
                                  a2 = packbf(wy.h, wy.r); a3 = a2; }
            else if (quad == 1) { a0 = packbf(wz.h, wz.r); a1 = a0;
                                  a2 = packbf(bb.h, bb.r); a3 = 0u; }
            else                { a0 = a1 = a2 = a3 = 0u; }
            A1c[t] = mk_frag(a0, a1, a2, a3);
        }

        auto evalCheap = [&](float px, float py, float pz) -> float {
            Split2 sx = split2(px), sy = split2(py), sz = split2(pz);
            unsigned d0, d1, d2, d3;
            if      (quad == 0) { d0 = packbf(sx.h, sx.h); d1 = packbf(sx.r, sx.r);
                                  d2 = packbf(sy.h, sy.h); d3 = packbf(sy.r, sy.r); }
            else if (quad == 1) { d0 = packbf(sz.h, sz.h); d1 = packbf(sz.r, sz.r);
                                  d2 = 0x3F803F80u;        d3 = 0u; }
            else                { d0 = d1 = d2 = d3 = 0u; }
            short8 B1 = mk_frag(d0, d1, d2, d3);

            const float4v z4 = {0.f, 0.f, 0.f, 0.f};
            float4v C1[4];
            #pragma unroll
            for (int t = 0; t < 4; ++t)
                C1[t] = __builtin_amdgcn_mfma_f32_16x16x32_bf16(A1c[t], B1, z4, 0, 0, 0);

            // relu + 2-split + in-lane pack
            unsigned PH[4][2], PM[4][2];
            #pragma unroll
            for (int t = 0; t < 4; ++t) {
                Split2 s0 = split2(fmaxf(C1[t][0], 0.f));
                Split2 s1 = split2(fmaxf(C1[t][1], 0.f));
                Split2 s2 = split2(fmaxf(C1[t][2], 0.f));
                Split2 s3 = split2(fmaxf(C1[t][3], 0.f));
                PH[t][0] = packbf(s0.h, s1.h); PH[t][1] = packbf(s2.h, s3.h);
                PM[t][0] = packbf(s0.r, s1.r); PM[t][1] = packbf(s2.r, s3.r);
            }
            short8 B2H[2], B2M[2];
            #pragma unroll
            for (int h = 0; h < 2; ++h) {
                B2H[h] = mk_frag(PH[2 * h][0], PH[2 * h][1],
                                 PH[2 * h + 1][0], PH[2 * h + 1][1]);
                B2M[h] = mk_frag(PM[2 * h][0], PM[2 * h][1],
                                 PM[2 * h + 1][0], PM[2 * h + 1][1]);
            }

            // L2: 4 products (MM, MH, HM, HH), 32 MFMAs, 8-deep chains
            float4v C2[4];
            #pragma unroll
            for (int t = 0; t < 4; ++t) C2[t] = b1v[t];
            #pragma unroll
            for (int h = 0; h < 2; ++h)
                #pragma unroll
                for (int t = 0; t < 4; ++t)
                    C2[t] = __builtin_amdgcn_mfma_f32_16x16x32_bf16(
                        A2[1][h][t], B2M[h], C2[t], 0, 0, 0);
            #pragma unroll
            for (int h = 0; h < 2; ++h)
                #pragma unroll
                for (int t = 0; t < 4; ++t)
                    C2[t] = __builtin_amdgcn_mfma_f32_16x16x32_bf16(
                        A2[1][h][t], B2H[h], C2[t], 0, 0, 0);
            #pragma unroll
            for (int h = 0; h < 2; ++h)
                #pragma unroll
                for (int t = 0; t < 4; ++t)
                    C2[t] = __builtin_amdgcn_mfma_f32_16x16x32_bf16(
                        A2[0][h][t], B2M[h], C2[t], 0, 0, 0);
            #pragma unroll
            for (int h = 0; h < 2; ++h)
                #pragma unroll
                for (int t = 0; t < 4; ++t)
                    C2[t] = __builtin_amdgcn_mfma_f32_16x16x32_bf16(
                        A2[0][h][t], B2H[h], C2[t], 0, 0, 0);

            float q0 = 0.f, q1 = 0.f, q2 = 0.f, q3 = 0.f;
            #pragma unroll
            for (int t = 0; t < 4; ++t) {
                q0 = fmaf(fmaxf(C2[t][0], 0.f), w2v[t][0], q0);
                q1 = fmaf(fmaxf(C2[t][1], 0.f), w2v[t][1], q1);
                q2 = fmaf(fmaxf(C2[t][2], 0.f), w2v[t][2], q2);
                q3 = fmaf(fmaxf(C2[t][3], 0.f), w2v[t][3], q3);
            }
            float part = (q0 + q1) + (q2 + q3);
            part += __shfl_xor(part, 16, 64);
            part += __shfl_xor(part, 32, 64);
            return b2s + part;
        };

        float cm = evalCheap(ox, oy, oz);
        #pragma unroll 1
        for (int i = 1; i <= 64; ++i) {
            float t_i = STEP_ * (float)i;
            cm = fminf(cm, evalCheap(fmaf(dx, t_i, ox), fmaf(dy, t_i, oy), fmaf(dz, t_i, oz)));
        }
        if (lane < 16)
            out[(rayBase + lane) * 4 + 3] = cm;
    }
}

extern "C" void kernel_launch(void* const* d_in, const int* in_sizes, int n_in,
                              void* d_out, int out_size, void* d_ws, size_t ws_size,
                              hipStream_t stream) {
    const float* rays = (const float*)d_in[0];
    const float* W0   = (const float*)d_in[1];
    const float* b0   = (const float*)d_in[2];
    const float* W1   = (const float*)d_in[3];
    const float* b1   = (const float*)d_in[4];
    const float* W2   = (const float*)d_in[5];
    const float* b2   = (const float*)d_in[6];
    const float* Wr0  = (const float*)d_in[7];
    const float* br0  = (const float*)d_in[8];
    const float* Wr1  = (const float*)d_in[9];
    const float* br1  = (const float*)d_in[10];
    float* out = (float*)d_out;

    // 1024 blocks x 4 waves: even blocks march (out.xyz), odd blocks tput (out.w).
    hipLaunchKernelGGL(sdf_tr3_k, dim3(NRAYS / 16 / 2), dim3(256), 0, stream,
                       rays, W0, b0, W1, b1, W2, b2, Wr0, br0, Wr1, br1, out);
}

// Round 8
// 227.372 us; speedup vs baseline: 1.1028x; 1.1028x over previous
//
#include <hip/hip_runtime.h>
#include <math.h>

// Problem constants
#define NRAYS        32768
#define MARCH_ITERS  64
#define EPS_         1e-4f
#define STEP_        ((1.0f + 1.0f/64.0f) / 64.0f)   // exact in fp32

typedef __attribute__((ext_vector_type(8)))  short    short8;   // 8 bf16
typedef __attribute__((ext_vector_type(4)))  float    float4v;  // C/D frag
typedef __attribute__((ext_vector_type(4)))  unsigned uint4v;

__device__ __forceinline__ short8 mk_frag(unsigned p0, unsigned p1,
                                          unsigned p2, unsigned p3) {
    uint4v v = {p0, p1, p2, p3};
    return __builtin_bit_cast(short8, v);
}

// One v_perm_b32: low16 = trunc-bf16(a), high16 = trunc-bf16(b).
__device__ __forceinline__ unsigned packbf(unsigned a, unsigned b) {
    return __builtin_amdgcn_perm(b, a, 0x07060302u);
}

// Exact 3-way truncation split: x == hi + mid + lo bit-exactly in fp32.
struct Split3 { unsigned h, m, l; };
__device__ __forceinline__ Split3 split3(float x) {
    unsigned xu = __float_as_uint(x);
    float xh = __uint_as_float(xu & 0xFFFF0000u);
    float r  = x - xh;                        // exact
    unsigned ru = __float_as_uint(r);
    float xm = __uint_as_float(ru & 0xFFFF0000u);
    float r2 = r - xm;                        // exact, fits bf16
    return { xu, ru, __float_as_uint(r2) };
}

// 2-way split (hi + residual; packbf truncates the residual = drops lo).
struct Split2 { unsigned h, r; };
__device__ __forceinline__ Split2 split2(float x) {
    unsigned xu = __float_as_uint(x);
    float xh = __uint_as_float(xu & 0xFFFF0000u);
    float rr = x - xh;                        // exact residual
    return { xu, __float_as_uint(rr) };
}

// One wave = 16 rays. Per loop iter: ONE march eval (exact 6-product) +
// ONE tput eval (cheap 4-product) interleaved -> 8 independent MFMA chains
// fill each other's latency. March iter0 position == tput t=0 point, so cm
// inits from dm (no separate 65th eval). Layouts verified R6:
//   A[row=lane&15][k=(lane>>4)*8+j]  B[k=(lane>>4)*8+j][col=lane&15]
//   C/D: col=lane&15, row=(lane>>4)*4+reg
//   L1 hidden assignment H(t,q,r)=32*(t>>1)+8q+4*(t&1)+r -> in-lane C1->B2.
__global__ __launch_bounds__(256, 2) void sdf_fused_k(
    const float* __restrict__ rays,
    const float* __restrict__ W0,  const float* __restrict__ b0,
    const float* __restrict__ W1,  const float* __restrict__ b1,
    const float* __restrict__ W2,  const float* __restrict__ b2,
    const float* __restrict__ Wr0, const float* __restrict__ br0,
    const float* __restrict__ Wr1, const float* __restrict__ br1,
    float* __restrict__ out)
{
    const int lane   = threadIdx.x & 63;
    const int waveId = threadIdx.x >> 6;
    const int quad   = lane >> 4;
    const int m      = lane & 15;
    const int rayBase = (blockIdx.x * 4 + waveId) * 16;

    // ---- per-lane ray (ray = rayBase + m, replicated over quads) ----
    const float* rp = rays + (rayBase + m) * 6;
    const float ox = rp[0], oy = rp[1], oz = rp[2];
    const float dx = rp[3], dy = rp[4], dz = rp[5];

    // ---- A2: W1^T splits in A-layout; [0]=hi,[1]=mid,[2]=lo (R6-verified) ----
    short8 A2[3][2][4];
    #pragma unroll
    for (int h = 0; h < 2; ++h)
        #pragma unroll
        for (int t = 0; t < 4; ++t) {
            unsigned ph[4], pm[4], pl[4];
            #pragma unroll
            for (int jp = 0; jp < 4; ++jp) {
                int k0 = 32 * h + quad * 8 + 2 * jp;
                int j2 = 16 * t + m;
                Split3 a = split3(W1[k0 * 64 + j2]);
                Split3 b = split3(W1[(k0 + 1) * 64 + j2]);
                ph[jp] = packbf(a.h, b.h);
                pm[jp] = packbf(a.m, b.m);
                pl[jp] = packbf(a.l, b.l);
            }
            A2[0][h][t] = mk_frag(ph[0], ph[1], ph[2], ph[3]);
            A2[1][h][t] = mk_frag(pm[0], pm[1], pm[2], pm[3]);
            A2[2][h][t] = mk_frag(pl[0], pl[1], pl[2], pl[3]);
        }

    // ---- A1: W0^T 3-splits + b0 in A-layout K-slots (21 slots, R6-verified) ----
    short8 A1[4];
    #pragma unroll
    for (int t = 0; t < 4; ++t) {
        int j = 32 * (t >> 1) + 8 * (m >> 2) + 4 * (t & 1) + (m & 3);
        Split3 wx = split3(W0[j]);
        Split3 wy = split3(W0[64 + j]);
        Split3 wz = split3(W0[128 + j]);
        Split3 bb = split3(b0[j]);
        unsigned a0, a1, a2, a3;
        if      (quad == 0) { a0 = packbf(wx.h, wx.m); a1 = packbf(wx.l, wx.h);
                              a2 = packbf(wx.m, wx.h); a3 = packbf(wy.h, wy.m); }
        else if (quad == 1) { a0 = packbf(wy.l, wy.h); a1 = packbf(wy.m, wy.h);
                              a2 = packbf(wz.h, wz.m); a3 = packbf(wz.l, wz.h); }
        else if (quad == 2) { a0 = packbf(wz.m, wz.h); a1 = packbf(bb.h, bb.m);
                              a2 = packbf(bb.l, 0u);   a3 = 0u; }
        else                { a0 = a1 = a2 = a3 = 0u; }
        A1[t] = mk_frag(a0, a1, a2, a3);
    }

    // ---- b1 (C2 init) and W2, per-lane rows j2 = 16t+4q+r ----
    float4v b1v[4], w2v[4];
    #pragma unroll
    for (int t = 0; t < 4; ++t) {
        int base = 16 * t + 4 * quad;
        b1v[t] = (float4v){b1[base], b1[base + 1], b1[base + 2], b1[base + 3]};
        w2v[t] = (float4v){W2[base], W2[base + 1], W2[base + 2], W2[base + 3]};
    }
    const float b2s = b2[0];

    // exact L1 B-fragment build (R6-verified 21-slot layout)
    auto buildB1 = [&](float px, float py, float pz) -> short8 {
        Split3 sx = split3(px), sy = split3(py), sz = split3(pz);
        unsigned d0, d1, d2, d3;
        if      (quad == 0) { d0 = packbf(sx.h, sx.h); d1 = packbf(sx.h, sx.m);
                              d2 = packbf(sx.m, sx.l); d3 = packbf(sy.h, sy.h); }
        else if (quad == 1) { d0 = packbf(sy.h, sy.m); d1 = packbf(sy.m, sy.l);
                              d2 = packbf(sz.h, sz.h); d3 = packbf(sz.h, sz.m); }
        else if (quad == 2) { d0 = packbf(sz.m, sz.l); d1 = 0x3F803F80u;
                              d2 = 0x00003F80u;        d3 = 0u; }
        else                { d0 = d1 = d2 = d3 = 0u; }
        return mk_frag(d0, d1, d2, d3);
    };

    // march L2 product order (sW, sH), small first; tput A-split order
    const int pw_[6] = {1, 2, 0, 1, 0, 0};
    const int ph_[6] = {1, 0, 2, 0, 1, 0};
    const int tpa[4] = {1, 1, 0, 0};          // (M,M)(M,H)(H,M)(H,H)

    const float4v z4 = {0.f, 0.f, 0.f, 0.f};
    bool  hit = false;
    float cd  = 0.f;
    float cm  = 0.f;                           // set from dm at it==0

    #pragma unroll 1
    for (int it = 0; it < MARCH_ITERS; ++it) {
        // ======== tput front-end (always): exact L1, 2-split pack ========
        float tt = STEP_ * (float)(it + 1);
        short8 B1t = buildB1(fmaf(dx, tt, ox), fmaf(dy, tt, oy), fmaf(dz, tt, oz));
        float4v C1t[4];
        #pragma unroll
        for (int t = 0; t < 4; ++t)
            C1t[t] = __builtin_amdgcn_mfma_f32_16x16x32_bf16(A1[t], B1t, z4, 0, 0, 0);
        unsigned PH[4][2], PM[4][2];
        #pragma unroll
        for (int t = 0; t < 4; ++t) {
            Split2 s0 = split2(fmaxf(C1t[t][0], 0.f));
            Split2 s1 = split2(fmaxf(C1t[t][1], 0.f));
            Split2 s2 = split2(fmaxf(C1t[t][2], 0.f));
            Split2 s3 = split2(fmaxf(C1t[t][3], 0.f));
            PH[t][0] = packbf(s0.h, s1.h); PH[t][1] = packbf(s2.h, s3.h);
            PM[t][0] = packbf(s0.r, s1.r); PM[t][1] = packbf(s2.r, s3.r);
        }
        short8 B2tH[2], B2tM[2];
        #pragma unroll
        for (int h = 0; h < 2; ++h) {
            B2tH[h] = mk_frag(PH[2 * h][0], PH[2 * h][1],
                              PH[2 * h + 1][0], PH[2 * h + 1][1]);
            B2tM[h] = mk_frag(PM[2 * h][0], PM[2 * h][1],
                              PM[2 * h + 1][0], PM[2 * h + 1][1]);
        }

        const bool doMarch = !__all((int)hit);
        float dt;
        if (doMarch) {
            // ======== march front-end: exact 6-product pipeline ========
            short8 B1m = buildB1(fmaf(dx, cd, ox), fmaf(dy, cd, oy), fmaf(dz, cd, oz));
            float4v C1m[4];
            #pragma unroll
            for (int t = 0; t < 4; ++t)
                C1m[t] = __builtin_amdgcn_mfma_f32_16x16x32_bf16(A1[t], B1m, z4, 0, 0, 0);
            unsigned P[3][4][2];
            #pragma unroll
            for (int t = 0; t < 4; ++t) {
                Split3 s0 = split3(fmaxf(C1m[t][0], 0.f));
                Split3 s1 = split3(fmaxf(C1m[t][1], 0.f));
                Split3 s2 = split3(fmaxf(C1m[t][2], 0.f));
                Split3 s3 = split3(fmaxf(C1m[t][3], 0.f));
                P[0][t][0] = packbf(s0.h, s1.h); P[0][t][1] = packbf(s2.h, s3.h);
                P[1][t][0] = packbf(s0.m, s1.m); P[1][t][1] = packbf(s2.m, s3.m);
                P[2][t][0] = packbf(s0.l, s1.l); P[2][t][1] = packbf(s2.l, s3.l);
            }
            short8 B2m[3][2];
            #pragma unroll
            for (int s = 0; s < 3; ++s)
                #pragma unroll
                for (int h = 0; h < 2; ++h)
                    B2m[s][h] = mk_frag(P[s][2 * h][0],     P[s][2 * h][1],
                                        P[s][2 * h + 1][0], P[s][2 * h + 1][1]);

            // ======== joint L2: 48 march + 32 tput MFMAs, 8 indep chains ====
            float4v C2m[4], C2t[4];
            #pragma unroll
            for (int t = 0; t < 4; ++t) { C2m[t] = b1v[t]; C2t[t] = b1v[t]; }
            #pragma unroll
            for (int p = 0; p < 6; ++p) {
                #pragma unroll
                for (int h = 0; h < 2; ++h)
                    #pragma unroll
                    for (int t = 0; t < 4; ++t)
                        C2m[t] = __builtin_amdgcn_mfma_f32_16x16x32_bf16(
                            A2[pw_[p]][h][t], B2m[ph_[p]][h], C2m[t], 0, 0, 0);
                if (p < 4) {
                    #pragma unroll
                    for (int h = 0; h < 2; ++h)
                        #pragma unroll
                        for (int t = 0; t < 4; ++t)
                            C2t[t] = __builtin_amdgcn_mfma_f32_16x16x32_bf16(
                                A2[tpa[p]][h][t], (p & 1) ? B2tH[h] : B2tM[h],
                                C2t[t], 0, 0, 0);
                }
            }

            // ======== L3 both + interleaved shuffles ========
            float qm0 = 0.f, qm1 = 0.f, qm2 = 0.f, qm3 = 0.f;
            float qt0 = 0.f, qt1 = 0.f, qt2 = 0.f, qt3 = 0.f;
            #pragma unroll
            for (int t = 0; t < 4; ++t) {
                qm0 = fmaf(fmaxf(C2m[t][0], 0.f), w2v[t][0], qm0);
                qm1 = fmaf(fmaxf(C2m[t][1], 0.f), w2v[t][1], qm1);
                qm2 = fmaf(fmaxf(C2m[t][2], 0.f), w2v[t][2], qm2);
                qm3 = fmaf(fmaxf(C2m[t][3], 0.f), w2v[t][3], qm3);
                qt0 = fmaf(fmaxf(C2t[t][0], 0.f), w2v[t][0], qt0);
                qt1 = fmaf(fmaxf(C2t[t][1], 0.f), w2v[t][1], qt1);
                qt2 = fmaf(fmaxf(C2t[t][2], 0.f), w2v[t][2], qt2);
                qt3 = fmaf(fmaxf(C2t[t][3], 0.f), w2v[t][3], qt3);
            }
            float pmv = (qm0 + qm1) + (qm2 + qm3);
            float ptv = (qt0 + qt1) + (qt2 + qt3);
            float pmv1 = __shfl_xor(pmv, 16, 64);
            float ptv1 = __shfl_xor(ptv, 16, 64);
            pmv += pmv1; ptv += ptv1;
            float pmv2 = __shfl_xor(pmv, 32, 64);
            float ptv2 = __shfl_xor(ptv, 32, 64);
            pmv += pmv2; ptv += ptv2;
            float dm = b2s + pmv;
            dt = b2s + ptv;

            // march state update (reference semantics)
            bool c = (dm < EPS_) && (cd >= 0.f) && (cd <= 1.f);
            hit = hit || c;
            if (!hit) cd += dm;
            if (it == 0) cm = dm;              // tput i=0 point == origin
        } else {
            // ======== tput-only L2 (all rays frozen) ========
            float4v C2t[4];
            #pragma unroll
            for (int t = 0; t < 4; ++t) C2t[t] = b1v[t];
            #pragma unroll
            for (int p = 0; p < 4; ++p)
                #pragma unroll
                for (int h = 0; h < 2; ++h)
                    #pragma unroll
                    for (int t = 0; t < 4; ++t)
                        C2t[t] = __builtin_amdgcn_mfma_f32_16x16x32_bf16(
                            A2[tpa[p]][h][t], (p & 1) ? B2tH[h] : B2tM[h],
                            C2t[t], 0, 0, 0);
            float qt0 = 0.f, qt1 = 0.f, qt2 = 0.f, qt3 = 0.f;
            #pragma unroll
            for (int t = 0; t < 4; ++t) {
                qt0 = fmaf(fmaxf(C2t[t][0], 0.f), w2v[t][0], qt0);
                qt1 = fmaf(fmaxf(C2t[t][1], 0.f), w2v[t][1], qt1);
                qt2 = fmaf(fmaxf(C2t[t][2], 0.f), w2v[t][2], qt2);
                qt3 = fmaf(fmaxf(C2t[t][3], 0.f), w2v[t][3], qt3);
            }
            float ptv = (qt0 + qt1) + (qt2 + qt3);
            ptv += __shfl_xor(ptv, 16, 64);
            ptv += __shfl_xor(ptv, 32, 64);
            dt = b2s + ptv;
        }
        cm = fminf(cm, dt);
    }

    // ---- reflection net: quad q handles hidden j in [16q, 16q+16) ----
    const float px = fmaf(dx, cd, ox), py = fmaf(dy, cd, oy), pz = fmaf(dz, cd, oz);
    float r0 = 0.f, r1 = 0.f, r2 = 0.f;
    #pragma unroll 4
    for (int jj = 0; jj < 16; ++jj) {
        int j = quad * 16 + jj;
        float a = fmaf(px, Wr0[j],
                  fmaf(py, Wr0[64 + j],
                  fmaf(pz, Wr0[128 + j],
                  fmaf(dx, Wr0[192 + j],
                  fmaf(dy, Wr0[256 + j],
                  fmaf(dz, Wr0[320 + j], br0[j]))))));
        a = fmaxf(a, 0.f);
        r0 = fmaf(a, Wr1[j * 3 + 0], r0);
        r1 = fmaf(a, Wr1[j * 3 + 1], r1);
        r2 = fmaf(a, Wr1[j * 3 + 2], r2);
    }
    r0 += __shfl_xor(r0, 16, 64); r0 += __shfl_xor(r0, 32, 64);
    r1 += __shfl_xor(r1, 16, 64); r1 += __shfl_xor(r1, 32, 64);
    r2 += __shfl_xor(r2, 16, 64); r2 += __shfl_xor(r2, 32, 64);
    r0 = 1.f / (1.f + expf(-(r0 + br1[0])));
    r1 = 1.f / (1.f + expf(-(r1 + br1[1])));
    r2 = 1.f / (1.f + expf(-(r2 + br1[2])));
    if (!hit) { r0 = 0.f; r1 = 0.f; r2 = 0.f; }

    if (lane < 16)
        reinterpret_cast<float4*>(out)[rayBase + lane] = make_float4(r0, r1, r2, cm);
}

extern "C" void kernel_launch(void* const* d_in, const int* in_sizes, int n_in,
                              void* d_out, int out_size, void* d_ws, size_t ws_size,
                              hipStream_t stream) {
    const float* rays = (const float*)d_in[0];
    const float* W0   = (const float*)d_in[1];
    const float* b0   = (const float*)d_in[2];
    const float* W1   = (const float*)d_in[3];
    const float* b1   = (const float*)d_in[4];
    const float* W2   = (const float*)d_in[5];
    const float* b2   = (const float*)d_in[6];
    const float* Wr0  = (const float*)d_in[7];
    const float* br0  = (const float*)d_in[8];
    const float* Wr1  = (const float*)d_in[9];
    const float* br1  = (const float*)d_in[10];
    float* out = (float*)d_out;

    // 512 blocks x 4 waves = 2048 waves (one per 16 rays), all co-resident:
    // march + tput fused per wave -> balanced load, ILP-overlapped chains.
    hipLaunchKernelGGL(sdf_fused_k, dim3(NRAYS / 64), dim3(256), 0, stream,
                       rays, W0, b0, W1, b1, W2, b2, Wr0, br0, Wr1, br1, out);
}

// Round 9
// 205.924 us; speedup vs baseline: 1.2177x; 1.1042x over previous
//
#include <hip/hip_runtime.h>
#include <math.h>

// Problem constants
#define NRAYS        32768
#define MARCH_ITERS  64
#define EPS_         1e-4f
#define STEP_        ((1.0f + 1.0f/64.0f) / 64.0f)   // exact in fp32

typedef __attribute__((ext_vector_type(8)))  short    short8;   // 8 bf16
typedef __attribute__((ext_vector_type(4)))  float    float4v;  // C/D frag
typedef __attribute__((ext_vector_type(4)))  unsigned uint4v;

__device__ __forceinline__ short8 mk_frag(unsigned p0, unsigned p1,
                                          unsigned p2, unsigned p3) {
    uint4v v = {p0, p1, p2, p3};
    return __builtin_bit_cast(short8, v);
}

// One v_perm_b32: low16 = trunc-bf16(a), high16 = trunc-bf16(b).
__device__ __forceinline__ unsigned packbf(unsigned a, unsigned b) {
    return __builtin_amdgcn_perm(b, a, 0x07060302u);
}

// Exact 3-way truncation split: x == hi + mid + lo bit-exactly in fp32.
struct Split3 { unsigned h, m, l; };
__device__ __forceinline__ Split3 split3(float x) {
    unsigned xu = __float_as_uint(x);
    float xh = __uint_as_float(xu & 0xFFFF0000u);
    float r  = x - xh;                        // exact
    unsigned ru = __float_as_uint(r);
    float xm = __uint_as_float(ru & 0xFFFF0000u);
    float r2 = r - xm;                        // exact, fits bf16
    return { xu, ru, __float_as_uint(r2) };
}

// One wave = 16 rays. Fused march (exact 6-product) + tput (3-product),
// software-pipelined: tput fragments for iter i+1 are built during march
// L2 of iter i. Branchless front-ends via uniform per-quad K-slots:
//   quad q<3 owns coord q, slots 8q+0..5 = [Wh*ph,Wh*pm,Wh*pl,Wm*ph,Wm*pm,Wl*ph]
//   quad 3 owns bias limbs, slots 24..26 = [bh,bm,bl] * 1.0
// MFMA layouts (R6-verified): A[row=lane&15][k=quad*8+j],
// B[k=quad*8+j][col=lane&15], C/D col=lane&15 row=quad*4+reg.
// L1 hidden assignment H(t,q,r)=32*(t>>1)+8q+4*(t&1)+r -> in-lane C1->B2.
__global__ __launch_bounds__(256, 2) void sdf_pipe_k(
    const float* __restrict__ rays,
    const float* __restrict__ W0,  const float* __restrict__ b0,
    const float* __restrict__ W1,  const float* __restrict__ b1,
    const float* __restrict__ W2,  const float* __restrict__ b2,
    const float* __restrict__ Wr0, const float* __restrict__ br0,
    const float* __restrict__ Wr1, const float* __restrict__ br1,
    float* __restrict__ out)
{
    const int lane   = threadIdx.x & 63;
    const int waveId = threadIdx.x >> 6;
    const int quad   = lane >> 4;
    const int m      = lane & 15;
    const int rayBase = (blockIdx.x * 4 + waveId) * 16;

    // ---- per-lane ray (ray = rayBase + m, replicated over quads) ----
    const float* rp = rays + (rayBase + m) * 6;
    const float ox = rp[0], oy = rp[1], oz = rp[2];
    const float dx = rp[3], dy = rp[4], dz = rp[5];

    // ---- A2: W1^T splits in A-layout; [0]=hi,[1]=mid,[2]=lo (R6-verified) ----
    short8 A2[3][2][4];
    #pragma unroll
    for (int h = 0; h < 2; ++h)
        #pragma unroll
        for (int t = 0; t < 4; ++t) {
            unsigned ph[4], pm[4], pl[4];
            #pragma unroll
            for (int jp = 0; jp < 4; ++jp) {
                int k0 = 32 * h + quad * 8 + 2 * jp;
                int j2 = 16 * t + m;
                Split3 a = split3(W1[k0 * 64 + j2]);
                Split3 b = split3(W1[(k0 + 1) * 64 + j2]);
                ph[jp] = packbf(a.h, b.h);
                pm[jp] = packbf(a.m, b.m);
                pl[jp] = packbf(a.l, b.l);
            }
            A2[0][h][t] = mk_frag(ph[0], ph[1], ph[2], ph[3]);
            A2[1][h][t] = mk_frag(pm[0], pm[1], pm[2], pm[3]);
            A2[2][h][t] = mk_frag(pl[0], pl[1], pl[2], pl[3]);
        }

    // ---- A1: uniform per-quad K-slot layout (one-time build) ----
    // quad<3: dwords (Wh,Wh)(Wh,Wm)(Wm,Wl)(0,0); quad3: (bh,bm)(bl,0)(0,0)(0,0)
    short8 A1[4];
    {
        const float* wbase = (quad == 0) ? W0 : (quad == 1) ? (W0 + 64)
                           : (quad == 2) ? (W0 + 128) : b0;
        #pragma unroll
        for (int t = 0; t < 4; ++t) {
            int j = 32 * (t >> 1) + 8 * (m >> 2) + 4 * (t & 1) + (m & 3);
            Split3 s = split3(wbase[j]);
            unsigned hh = packbf(s.h, s.h);
            unsigned hm = packbf(s.h, s.m);
            unsigned ml = packbf(s.m, s.l);
            unsigned l0 = packbf(s.l, 0u);
            bool is3 = (quad == 3);
            A1[t] = mk_frag(is3 ? hm : hh, is3 ? l0 : hm, is3 ? 0u : ml, 0u);
        }
    }

    // ---- b1 (C2 init) and W2, per-lane rows j2 = 16t+4q+r ----
    float4v b1v[4], w2v[4];
    #pragma unroll
    for (int t = 0; t < 4; ++t) {
        int base = 16 * t + 4 * quad;
        b1v[t] = (float4v){b1[base], b1[base + 1], b1[base + 2], b1[base + 3]};
        w2v[t] = (float4v){W2[base], W2[base + 1], W2[base + 2], W2[base + 3]};
    }
    const float b2s = b2[0];
    const float4v z4 = {0.f, 0.f, 0.f, 0.f};

    // ---- branchless B1 build (per eval): ~16 flat VALU ----
    auto buildB1 = [&](float px, float py, float pz) -> short8 {
        float c = (quad == 0) ? px : (quad == 1) ? py : pz;   // 2 cndmask
        Split3 s = split3(c);
        unsigned d0 = packbf(s.h, s.m);
        unsigned d1 = packbf(s.l, s.h);
        unsigned d2 = packbf(s.m, s.h);
        if (quad == 3) { d0 = 0x3F803F80u; d1 = 0x00003F80u; d2 = 0u; } // cndmask x3
        return mk_frag(d0, d1, d2, 0u);
    };

    // ---- tput front-end: position -> L1 -> 2-split packed B fragments ----
    auto tputFront = [&](float tt, short8* BH, short8* BM) {
        short8 B1t = buildB1(fmaf(dx, tt, ox), fmaf(dy, tt, oy), fmaf(dz, tt, oz));
        float4v C1t[4];
        #pragma unroll
        for (int t = 0; t < 4; ++t)
            C1t[t] = __builtin_amdgcn_mfma_f32_16x16x32_bf16(A1[t], B1t, z4, 0, 0, 0);
        unsigned PH[4][2], PM[4][2];
        #pragma unroll
        for (int t = 0; t < 4; ++t) {
            float v0 = fmaxf(C1t[t][0], 0.f), v1 = fmaxf(C1t[t][1], 0.f);
            float v2 = fmaxf(C1t[t][2], 0.f), v3 = fmaxf(C1t[t][3], 0.f);
            unsigned u0 = __float_as_uint(v0), u1 = __float_as_uint(v1);
            unsigned u2 = __float_as_uint(v2), u3 = __float_as_uint(v3);
            PH[t][0] = packbf(u0, u1); PH[t][1] = packbf(u2, u3);
            float r0 = v0 - __uint_as_float(u0 & 0xFFFF0000u);
            float r1 = v1 - __uint_as_float(u1 & 0xFFFF0000u);
            float r2 = v2 - __uint_as_float(u2 & 0xFFFF0000u);
            float r3 = v3 - __uint_as_float(u3 & 0xFFFF0000u);
            PM[t][0] = packbf(__float_as_uint(r0), __float_as_uint(r1));
            PM[t][1] = packbf(__float_as_uint(r2), __float_as_uint(r3));
        }
        #pragma unroll
        for (int h = 0; h < 2; ++h) {
            BH[h] = mk_frag(PH[2 * h][0], PH[2 * h][1],
                            PH[2 * h + 1][0], PH[2 * h + 1][1]);
            BM[h] = mk_frag(PM[2 * h][0], PM[2 * h][1],
                            PM[2 * h + 1][0], PM[2 * h + 1][1]);
        }
    };

    // ---- tput L2: 3 products (Wm*H, Wh*R, Wh*H), small first; 24 MFMAs ----
    auto tputL2 = [&](const short8* BH, const short8* BM, float4v* C2t) {
        #pragma unroll
        for (int t = 0; t < 4; ++t) C2t[t] = b1v[t];
        #pragma unroll
        for (int h = 0; h < 2; ++h)
            #pragma unroll
            for (int t = 0; t < 4; ++t)
                C2t[t] = __builtin_amdgcn_mfma_f32_16x16x32_bf16(
                    A2[1][h][t], BH[h], C2t[t], 0, 0, 0);
        #pragma unroll
        for (int h = 0; h < 2; ++h)
            #pragma unroll
            for (int t = 0; t < 4; ++t)
                C2t[t] = __builtin_amdgcn_mfma_f32_16x16x32_bf16(
                    A2[0][h][t], BM[h], C2t[t], 0, 0, 0);
        #pragma unroll
        for (int h = 0; h < 2; ++h)
            #pragma unroll
            for (int t = 0; t < 4; ++t)
                C2t[t] = __builtin_amdgcn_mfma_f32_16x16x32_bf16(
                    A2[0][h][t], BH[h], C2t[t], 0, 0, 0);
    };

    // ---- L3: in-lane relu*W2, 2 cross-quad shuffles -> d at every lane ----
    auto l3 = [&](const float4v* C2) -> float {
        float q0 = 0.f, q1 = 0.f, q2 = 0.f, q3 = 0.f;
        #pragma unroll
        for (int t = 0; t < 4; ++t) {
            q0 = fmaf(fmaxf(C2[t][0], 0.f), w2v[t][0], q0);
            q1 = fmaf(fmaxf(C2[t][1], 0.f), w2v[t][1], q1);
            q2 = fmaf(fmaxf(C2[t][2], 0.f), w2v[t][2], q2);
            q3 = fmaf(fmaxf(C2[t][3], 0.f), w2v[t][3], q3);
        }
        float part = (q0 + q1) + (q2 + q3);
        part += __shfl_xor(part, 16, 64);
        part += __shfl_xor(part, 32, 64);
        return b2s + part;
    };

    // march L2 product order (sW, sH), small first: (m,m)(l,h)(h,l)(m,h)(h,m)(h,h)
    const int pw_[6] = {1, 2, 0, 1, 0, 0};
    const int ph_[6] = {1, 0, 2, 0, 1, 0};

    bool  hit = false;
    float cd  = 0.f;
    float cm  = 0.f;                           // set from dm at it==0

    // pipeline prologue: tput fragments for iter 0 (t = STEP*1)
    short8 BtH[2], BtM[2];
    tputFront(STEP_, BtH, BtM);

    #pragma unroll 1
    for (int it = 0; it < MARCH_ITERS; ++it) {
        const bool doMarch = !__all((int)hit);
        float dt;
        // tput fragments for NEXT iter (t = STEP*(it+2)); harmless overrun at it=63
        short8 BnH[2], BnM[2];
        if (doMarch) {
            // march front-end: exact 6-product L1 + pack
            short8 B1m = buildB1(fmaf(dx, cd, ox), fmaf(dy, cd, oy), fmaf(dz, cd, oz));
            float4v C1m[4];
            #pragma unroll
            for (int t = 0; t < 4; ++t)
                C1m[t] = __builtin_amdgcn_mfma_f32_16x16x32_bf16(A1[t], B1m, z4, 0, 0, 0);
            // tput L2 for current iter (independent -> overlaps march front)
            float4v C2t[4];
            tputL2(BtH, BtM, C2t);
            // march pack: relu + exact 3-split + in-lane B2m assembly
            unsigned P[3][4][2];
            #pragma unroll
            for (int t = 0; t < 4; ++t) {
                Split3 s0 = split3(fmaxf(C1m[t][0], 0.f));
                Split3 s1 = split3(fmaxf(C1m[t][1], 0.f));
                Split3 s2 = split3(fmaxf(C1m[t][2], 0.f));
                Split3 s3 = split3(fmaxf(C1m[t][3], 0.f));
                P[0][t][0] = packbf(s0.h, s1.h); P[0][t][1] = packbf(s2.h, s3.h);
                P[1][t][0] = packbf(s0.m, s1.m); P[1][t][1] = packbf(s2.m, s3.m);
                P[2][t][0] = packbf(s0.l, s1.l); P[2][t][1] = packbf(s2.l, s3.l);
            }
            short8 B2m[3][2];
            #pragma unroll
            for (int s = 0; s < 3; ++s)
                #pragma unroll
                for (int h = 0; h < 2; ++h)
                    B2m[s][h] = mk_frag(P[s][2 * h][0],     P[s][2 * h][1],
                                        P[s][2 * h + 1][0], P[s][2 * h + 1][1]);
            // march L2 (48 MFMAs) — next-iter tput front-end VALU overlaps this
            float4v C2m[4];
            #pragma unroll
            for (int t = 0; t < 4; ++t) C2m[t] = b1v[t];
            #pragma unroll
            for (int p = 0; p < 6; ++p)
                #pragma unroll
                for (int h = 0; h < 2; ++h)
                    #pragma unroll
                    for (int t = 0; t < 4; ++t)
                        C2m[t] = __builtin_amdgcn_mfma_f32_16x16x32_bf16(
                            A2[pw_[p]][h][t], B2m[ph_[p]][h], C2m[t], 0, 0, 0);
            tputFront(STEP_ * (float)(it + 2), BnH, BnM);
            // L3 both
            float dm = l3(C2m);
            dt = l3(C2t);
            bool c = (dm < EPS_) && (cd >= 0.f) && (cd <= 1.f);
            hit = hit || c;
            if (!hit) cd += dm;
            if (it == 0) cm = dm;              // tput i=0 point == origin eval
        } else {
            float4v C2t[4];
            tputL2(BtH, BtM, C2t);
            tputFront(STEP_ * (float)(it + 2), BnH, BnM);
            dt = l3(C2t);
        }
        cm = fminf(cm, dt);
        #pragma unroll
        for (int h = 0; h < 2; ++h) { BtH[h] = BnH[h]; BtM[h] = BnM[h]; }
    }

    // ---- reflection net: quad q handles hidden j in [16q, 16q+16) ----
    const float px = fmaf(dx, cd, ox), py = fmaf(dy, cd, oy), pz = fmaf(dz, cd, oz);
    float r0 = 0.f, r1 = 0.f, r2 = 0.f;
    #pragma unroll 4
    for (int jj = 0; jj < 16; ++jj) {
        int j = quad * 16 + jj;
        float a = fmaf(px, Wr0[j],
                  fmaf(py, Wr0[64 + j],
                  fmaf(pz, Wr0[128 + j],
                  fmaf(dx, Wr0[192 + j],
                  fmaf(dy, Wr0[256 + j],
                  fmaf(dz, Wr0[320 + j], br0[j]))))));
        a = fmaxf(a, 0.f);
        r0 = fmaf(a, Wr1[j * 3 + 0], r0);
        r1 = fmaf(a, Wr1[j * 3 + 1], r1);
        r2 = fmaf(a, Wr1[j * 3 + 2], r2);
    }
    r0 += __shfl_xor(r0, 16, 64); r0 += __shfl_xor(r0, 32, 64);
    r1 += __shfl_xor(r1, 16, 64); r1 += __shfl_xor(r1, 32, 64);
    r2 += __shfl_xor(r2, 16, 64); r2 += __shfl_xor(r2, 32, 64);
    r0 = 1.f / (1.f + expf(-(r0 + br1[0])));
    r1 = 1.f / (1.f + expf(-(r1 + br1[1])));
    r2 = 1.f / (1.f + expf(-(r2 + br1[2])));
    if (!hit) { r0 = 0.f; r1 = 0.f; r2 = 0.f; }

    if (lane < 16)
        reinterpret_cast<float4*>(out)[rayBase + lane] = make_float4(r0, r1, r2, cm);
}

extern "C" void kernel_launch(void* const* d_in, const int* in_sizes, int n_in,
                              void* d_out, int out_size, void* d_ws, size_t ws_size,
                              hipStream_t stream) {
    const float* rays = (const float*)d_in[0];
    const float* W0   = (const float*)d_in[1];
    const float* b0   = (const float*)d_in[2];
    const float* W1   = (const float*)d_in[3];
    const float* b1   = (const float*)d_in[4];
    const float* W2   = (const float*)d_in[5];
    const float* b2   = (const float*)d_in[6];
    const float* Wr0  = (const float*)d_in[7];
    const float* br0  = (const float*)d_in[8];
    const float* Wr1  = (const float*)d_in[9];
    const float* br1  = (const float*)d_in[10];
    float* out = (float*)d_out;

    // 512 blocks x 4 waves = 2048 waves (16 rays each), fused march+tput,
    // software-pipelined; 2 waves/SIMD resident.
    hipLaunchKernelGGL(sdf_pipe_k, dim3(NRAYS / 64), dim3(256), 0, stream,
                       rays, W0, b0, W1, b1, W2, b2, Wr0, br0, Wr1, br1, out);
}

// Round 10
// 201.518 us; speedup vs baseline: 1.2443x; 1.0219x over previous
//
#include <hip/hip_runtime.h>
#include <math.h>

// Problem constants
#define NRAYS        32768
#define MARCH_ITERS  64
#define EPS_         1e-4f
#define STEP_        ((1.0f + 1.0f/64.0f) / 64.0f)   // exact in fp32

typedef __attribute__((ext_vector_type(8)))  short    short8;   // 8 bf16
typedef __attribute__((ext_vector_type(4)))  float    float4v;  // C/D frag
typedef __attribute__((ext_vector_type(4)))  unsigned uint4v;

__device__ __forceinline__ short8 mk_frag(unsigned p0, unsigned p1,
                                          unsigned p2, unsigned p3) {
    uint4v v = {p0, p1, p2, p3};
    return __builtin_bit_cast(short8, v);
}

// One v_perm_b32: low16 = trunc-bf16(a), high16 = trunc-bf16(b).
__device__ __forceinline__ unsigned packbf(unsigned a, unsigned b) {
    return __builtin_amdgcn_perm(b, a, 0x07060302u);
}

// Exact 3-way truncation split: x == hi + mid + lo bit-exactly in fp32.
struct Split3 { unsigned h, m, l; };
__device__ __forceinline__ Split3 split3(float x) {
    unsigned xu = __float_as_uint(x);
    float xh = __uint_as_float(xu & 0xFFFF0000u);
    float r  = x - xh;                        // exact
    unsigned ru = __float_as_uint(r);
    float xm = __uint_as_float(ru & 0xFFFF0000u);
    float r2 = r - xm;                        // exact, fits bf16
    return { xu, ru, __float_as_uint(r2) };
}

// 2-way split: hi + residual (packbf of r truncates -> the mid limb).
struct Split2 { unsigned h, r; };
__device__ __forceinline__ Split2 split2(float x) {
    unsigned xu = __float_as_uint(x);
    float xh = __uint_as_float(xu & 0xFFFF0000u);
    float rr = x - xh;                        // exact residual
    return { xu, __float_as_uint(rr) };
}

// One wave = 16 rays. Fused march (5-product) + tput (3-product), software-
// pipelined; wave phase-skew via s_sleep on odd waves. Branchless front-ends
// (uniform per-quad K-slots). MFMA layouts (R6-verified):
//   A[row=lane&15][k=quad*8+j], B[k=quad*8+j][col=lane&15],
//   C/D col=lane&15 row=quad*4+reg.
// L1 hidden assignment H(t,q,r)=32*(t>>1)+8q+4*(t&1)+r -> in-lane C1->B2.
__global__ __launch_bounds__(256, 2) void sdf_p5_k(
    const float* __restrict__ rays,
    const float* __restrict__ W0,  const float* __restrict__ b0,
    const float* __restrict__ W1,  const float* __restrict__ b1,
    const float* __restrict__ W2,  const float* __restrict__ b2,
    const float* __restrict__ Wr0, const float* __restrict__ br0,
    const float* __restrict__ Wr1, const float* __restrict__ br1,
    float* __restrict__ out)
{
    const int lane   = threadIdx.x & 63;
    const int waveId = threadIdx.x >> 6;
    const int quad   = lane >> 4;
    const int m      = lane & 15;
    const int rayBase = (blockIdx.x * 4 + waveId) * 16;

    // ---- per-lane ray (ray = rayBase + m, replicated over quads) ----
    const float* rp = rays + (rayBase + m) * 6;
    const float ox = rp[0], oy = rp[1], oz = rp[2];
    const float dx = rp[3], dy = rp[4], dz = rp[5];

    // ---- A2: W1^T hi/mid limbs in A-layout (16 frags = 64 VGPRs) ----
    // (lo limb dropped: its only product Wl*ph ~2e-6 abs in d — R10 change)
    short8 A2[2][2][4];
    #pragma unroll
    for (int h = 0; h < 2; ++h)
        #pragma unroll
        for (int t = 0; t < 4; ++t) {
            unsigned ph[4], pm[4];
            #pragma unroll
            for (int jp = 0; jp < 4; ++jp) {
                int k0 = 32 * h + quad * 8 + 2 * jp;
                int j2 = 16 * t + m;
                Split2 a = split2(W1[k0 * 64 + j2]);
                Split2 b = split2(W1[(k0 + 1) * 64 + j2]);
                ph[jp] = packbf(a.h, b.h);
                pm[jp] = packbf(a.r, b.r);     // trunc(residual) == mid limb
            }
            A2[0][h][t] = mk_frag(ph[0], ph[1], ph[2], ph[3]);
            A2[1][h][t] = mk_frag(pm[0], pm[1], pm[2], pm[3]);
        }

    // ---- A1: uniform per-quad K-slot layout (one-time build) ----
    // quad<3: dwords (Wh,Wh)(Wh,Wm)(Wm,Wl)(0,0); quad3: (bh,bm)(bl,0)(0,0)(0,0)
    short8 A1[4];
    {
        const float* wbase = (quad == 0) ? W0 : (quad == 1) ? (W0 + 64)
                           : (quad == 2) ? (W0 + 128) : b0;
        #pragma unroll
        for (int t = 0; t < 4; ++t) {
            int j = 32 * (t >> 1) + 8 * (m >> 2) + 4 * (t & 1) + (m & 3);
            Split3 s = split3(wbase[j]);
            unsigned hh = packbf(s.h, s.h);
            unsigned hm = packbf(s.h, s.m);
            unsigned ml = packbf(s.m, s.l);
            unsigned l0 = packbf(s.l, 0u);
            bool is3 = (quad == 3);
            A1[t] = mk_frag(is3 ? hm : hh, is3 ? l0 : hm, is3 ? 0u : ml, 0u);
        }
    }

    // ---- b1 (C2 init) and W2, per-lane rows j2 = 16t+4q+r ----
    float4v b1v[4], w2v[4];
    #pragma unroll
    for (int t = 0; t < 4; ++t) {
        int base = 16 * t + 4 * quad;
        b1v[t] = (float4v){b1[base], b1[base + 1], b1[base + 2], b1[base + 3]};
        w2v[t] = (float4v){W2[base], W2[base + 1], W2[base + 2], W2[base + 3]};
    }
    const float b2s = b2[0];
    const float4v z4 = {0.f, 0.f, 0.f, 0.f};

    // ---- branchless B1 build (per eval) ----
    auto buildB1 = [&](float px, float py, float pz) -> short8 {
        float c = (quad == 0) ? px : (quad == 1) ? py : pz;   // 2 cndmask
        Split3 s = split3(c);
        unsigned d0 = packbf(s.h, s.m);
        unsigned d1 = packbf(s.l, s.h);
        unsigned d2 = packbf(s.m, s.h);
        if (quad == 3) { d0 = 0x3F803F80u; d1 = 0x00003F80u; d2 = 0u; } // cndmask x3
        return mk_frag(d0, d1, d2, 0u);
    };

    // ---- tput front-end: position -> L1 -> 2-split packed B fragments ----
    auto tputFront = [&](float tt, short8* BH, short8* BM) {
        short8 B1t = buildB1(fmaf(dx, tt, ox), fmaf(dy, tt, oy), fmaf(dz, tt, oz));
        float4v C1t[4];
        #pragma unroll
        for (int t = 0; t < 4; ++t)
            C1t[t] = __builtin_amdgcn_mfma_f32_16x16x32_bf16(A1[t], B1t, z4, 0, 0, 0);
        unsigned PH[4][2], PM[4][2];
        #pragma unroll
        for (int t = 0; t < 4; ++t) {
            float v0 = fmaxf(C1t[t][0], 0.f), v1 = fmaxf(C1t[t][1], 0.f);
            float v2 = fmaxf(C1t[t][2], 0.f), v3 = fmaxf(C1t[t][3], 0.f);
            unsigned u0 = __float_as_uint(v0), u1 = __float_as_uint(v1);
            unsigned u2 = __float_as_uint(v2), u3 = __float_as_uint(v3);
            PH[t][0] = packbf(u0, u1); PH[t][1] = packbf(u2, u3);
            float r0 = v0 - __uint_as_float(u0 & 0xFFFF0000u);
            float r1 = v1 - __uint_as_float(u1 & 0xFFFF0000u);
            float r2 = v2 - __uint_as_float(u2 & 0xFFFF0000u);
            float r3 = v3 - __uint_as_float(u3 & 0xFFFF0000u);
            PM[t][0] = packbf(__float_as_uint(r0), __float_as_uint(r1));
            PM[t][1] = packbf(__float_as_uint(r2), __float_as_uint(r3));
        }
        #pragma unroll
        for (int h = 0; h < 2; ++h) {
            BH[h] = mk_frag(PH[2 * h][0], PH[2 * h][1],
                            PH[2 * h + 1][0], PH[2 * h + 1][1]);
            BM[h] = mk_frag(PM[2 * h][0], PM[2 * h][1],
                            PM[2 * h + 1][0], PM[2 * h + 1][1]);
        }
    };

    // ---- L3: in-lane relu*W2, 2 cross-quad shuffles -> d at every lane ----
    auto l3 = [&](const float4v* C2) -> float {
        float q0 = 0.f, q1 = 0.f, q2 = 0.f, q3 = 0.f;
        #pragma unroll
        for (int t = 0; t < 4; ++t) {
            q0 = fmaf(fmaxf(C2[t][0], 0.f), w2v[t][0], q0);
            q1 = fmaf(fmaxf(C2[t][1], 0.f), w2v[t][1], q1);
            q2 = fmaf(fmaxf(C2[t][2], 0.f), w2v[t][2], q2);
            q3 = fmaf(fmaxf(C2[t][3], 0.f), w2v[t][3], q3);
        }
        float part = (q0 + q1) + (q2 + q3);
        part += __shfl_xor(part, 16, 64);
        part += __shfl_xor(part, 32, 64);
        return b2s + part;
    };

    // ---- tput L2: 3 products (Wm*H, Wh*R, Wh*H), small first; 24 MFMAs ----
    auto tputL2 = [&](const short8* BH, const short8* BM, float4v* C2t) {
        #pragma unroll
        for (int t = 0; t < 4; ++t) C2t[t] = b1v[t];
        #pragma unroll
        for (int h = 0; h < 2; ++h)
            #pragma unroll
            for (int t = 0; t < 4; ++t)
                C2t[t] = __builtin_amdgcn_mfma_f32_16x16x32_bf16(
                    A2[1][h][t], BH[h], C2t[t], 0, 0, 0);
        #pragma unroll
        for (int h = 0; h < 2; ++h)
            #pragma unroll
            for (int t = 0; t < 4; ++t)
                C2t[t] = __builtin_amdgcn_mfma_f32_16x16x32_bf16(
                    A2[0][h][t], BM[h], C2t[t], 0, 0, 0);
        #pragma unroll
        for (int h = 0; h < 2; ++h)
            #pragma unroll
            for (int t = 0; t < 4; ++t)
                C2t[t] = __builtin_amdgcn_mfma_f32_16x16x32_bf16(
                    A2[0][h][t], BH[h], C2t[t], 0, 0, 0);
    };

    // march L2 product order (sW in {0=h,1=m}, sH in {0=h,1=m,2=l}), small
    // first: (m,m)(h,l)(m,h)(h,m)(h,h) — 5 products, 40 MFMAs.
    const int pw_[5] = {1, 0, 1, 0, 0};
    const int ph_[5] = {1, 2, 0, 1, 0};

    bool  hit = false;
    float cd  = 0.f;
    float cm  = 0.f;                           // set from dm at it==0

    // pipeline prologue: tput fragments for iter 0 (t = STEP*1)
    short8 BtH[2], BtM[2];
    tputFront(STEP_, BtH, BtM);

    // ---- phase-skew: odd waves sleep ~1.3k cyc so the 2 resident waves
    // stop hitting the serial march sections in lockstep ----
    if (waveId & 1) {
        __builtin_amdgcn_s_sleep(7);
        __builtin_amdgcn_s_sleep(7);
        __builtin_amdgcn_s_sleep(7);
    }

    #pragma unroll 1
    for (int it = 0; it < MARCH_ITERS; ++it) {
        const bool doMarch = !__all((int)hit);
        float dt;
        short8 BnH[2], BnM[2];
        if (doMarch) {
            // march front-end: exact L1 + 3-split pack
            short8 B1m = buildB1(fmaf(dx, cd, ox), fmaf(dy, cd, oy), fmaf(dz, cd, oz));
            float4v C1m[4];
            #pragma unroll
            for (int t = 0; t < 4; ++t)
                C1m[t] = __builtin_amdgcn_mfma_f32_16x16x32_bf16(A1[t], B1m, z4, 0, 0, 0);
            unsigned P[3][4][2];
            #pragma unroll
            for (int t = 0; t < 4; ++t) {
                Split3 s0 = split3(fmaxf(C1m[t][0], 0.f));
                Split3 s1 = split3(fmaxf(C1m[t][1], 0.f));
                Split3 s2 = split3(fmaxf(C1m[t][2], 0.f));
                Split3 s3 = split3(fmaxf(C1m[t][3], 0.f));
                P[0][t][0] = packbf(s0.h, s1.h); P[0][t][1] = packbf(s2.h, s3.h);
                P[1][t][0] = packbf(s0.m, s1.m); P[1][t][1] = packbf(s2.m, s3.m);
                P[2][t][0] = packbf(s0.l, s1.l); P[2][t][1] = packbf(s2.l, s3.l);
            }
            short8 B2m[3][2];
            #pragma unroll
            for (int s = 0; s < 3; ++s)
                #pragma unroll
                for (int h = 0; h < 2; ++h)
                    B2m[s][h] = mk_frag(P[s][2 * h][0],     P[s][2 * h][1],
                                        P[s][2 * h + 1][0], P[s][2 * h + 1][1]);

            // merged L2: march 5 products (40 MFMA) interleaved with tput
            // 3 products (24 MFMA) at 8-MFMA group granularity
            float4v C2m[4], C2t[4];
            #pragma unroll
            for (int t = 0; t < 4; ++t) { C2m[t] = b1v[t]; C2t[t] = b1v[t]; }
            #pragma unroll
            for (int p = 0; p < 5; ++p) {
                #pragma unroll
                for (int h = 0; h < 2; ++h)
                    #pragma unroll
                    for (int t = 0; t < 4; ++t)
                        C2m[t] = __builtin_amdgcn_mfma_f32_16x16x32_bf16(
                            A2[pw_[p]][h][t], B2m[ph_[p]][h], C2m[t], 0, 0, 0);
                if (p < 3) {
                    const short8* Bt = (p == 1) ? BtM : BtH;
                    const int sw = (p == 0) ? 1 : 0;
                    #pragma unroll
                    for (int h = 0; h < 2; ++h)
                        #pragma unroll
                        for (int t = 0; t < 4; ++t)
                            C2t[t] = __builtin_amdgcn_mfma_f32_16x16x32_bf16(
                                A2[sw][h][t], Bt[h], C2t[t], 0, 0, 0);
                }
            }
            // next-iter tput front-end overlaps the L2/L3 tail
            tputFront(STEP_ * (float)(it + 2), BnH, BnM);
            float dm = l3(C2m);
            dt = l3(C2t);
            bool c = (dm < EPS_) && (cd >= 0.f) && (cd <= 1.f);
            hit = hit || c;
            if (!hit) cd += dm;
            if (it == 0) cm = dm;              // tput i=0 point == origin eval
        } else {
            float4v C2t[4];
            tputL2(BtH, BtM, C2t);
            tputFront(STEP_ * (float)(it + 2), BnH, BnM);
            dt = l3(C2t);
        }
        cm = fminf(cm, dt);
        #pragma unroll
        for (int h = 0; h < 2; ++h) { BtH[h] = BnH[h]; BtM[h] = BnM[h]; }
    }

    // ---- reflection net: quad q handles hidden j in [16q, 16q+16) ----
    const float px = fmaf(dx, cd, ox), py = fmaf(dy, cd, oy), pz = fmaf(dz, cd, oz);
    float r0 = 0.f, r1 = 0.f, r2 = 0.f;
    #pragma unroll 4
    for (int jj = 0; jj < 16; ++jj) {
        int j = quad * 16 + jj;
        float a = fmaf(px, Wr0[j],
                  fmaf(py, Wr0[64 + j],
                  fmaf(pz, Wr0[128 + j],
                  fmaf(dx, Wr0[192 + j],
                  fmaf(dy, Wr0[256 + j],
                  fmaf(dz, Wr0[320 + j], br0[j]))))));
        a = fmaxf(a, 0.f);
        r0 = fmaf(a, Wr1[j * 3 + 0], r0);
        r1 = fmaf(a, Wr1[j * 3 + 1], r1);
        r2 = fmaf(a, Wr1[j * 3 + 2], r2);
    }
    r0 += __shfl_xor(r0, 16, 64); r0 += __shfl_xor(r0, 32, 64);
    r1 += __shfl_xor(r1, 16, 64); r1 += __shfl_xor(r1, 32, 64);
    r2 += __shfl_xor(r2, 16, 64); r2 += __shfl_xor(r2, 32, 64);
    r0 = 1.f / (1.f + expf(-(r0 + br1[0])));
    r1 = 1.f / (1.f + expf(-(r1 + br1[1])));
    r2 = 1.f / (1.f + expf(-(r2 + br1[2])));
    if (!hit) { r0 = 0.f; r1 = 0.f; r2 = 0.f; }

    if (lane < 16)
        reinterpret_cast<float4*>(out)[rayBase + lane] = make_float4(r0, r1, r2, cm);
}

extern "C" void kernel_launch(void* const* d_in, const int* in_sizes, int n_in,
                              void* d_out, int out_size, void* d_ws, size_t ws_size,
                              hipStream_t stream) {
    const float* rays = (const float*)d_in[0];
    const float* W0   = (const float*)d_in[1];
    const float* b0   = (const float*)d_in[2];
    const float* W1   = (const float*)d_in[3];
    const float* b1   = (const float*)d_in[4];
    const float* W2   = (const float*)d_in[5];
    const float* b2   = (const float*)d_in[6];
    const float* Wr0  = (const float*)d_in[7];
    const float* br0  = (const float*)d_in[8];
    const float* Wr1  = (const float*)d_in[9];
    const float* br1  = (const float*)d_in[10];
    float* out = (float*)d_out;

    // 512 blocks x 4 waves = 2048 waves (16 rays each), fused march+tput,
    // 5-product march L2, phase-skewed waves; 2 waves/SIMD resident.
    hipLaunchKernelGGL(sdf_p5_k, dim3(NRAYS / 64), dim3(256), 0, stream,
                       rays, W0, b0, W1, b1, W2, b2, Wr0, br0, Wr1, br1, out);
}

// Round 11
// 188.044 us; speedup vs baseline: 1.3335x; 1.0717x over previous
//
#include <hip/hip_runtime.h>
#include <math.h>

// Problem constants
#define NRAYS        32768
#define MARCH_ITERS  64
#define EPS_         1e-4f
#define STEP_        ((1.0f + 1.0f/64.0f) / 64.0f)   // exact in fp32

typedef __attribute__((ext_vector_type(8)))  short    short8;   // 8 bf16
typedef __attribute__((ext_vector_type(4)))  float    float4v;  // C/D frag
typedef __attribute__((ext_vector_type(4)))  unsigned uint4v;

__device__ __forceinline__ short8 mk_frag(unsigned p0, unsigned p1,
                                          unsigned p2, unsigned p3) {
    uint4v v = {p0, p1, p2, p3};
    return __builtin_bit_cast(short8, v);
}

// One v_perm_b32: low16 = trunc-bf16(a), high16 = trunc-bf16(b).
__device__ __forceinline__ unsigned packbf(unsigned a, unsigned b) {
    return __builtin_amdgcn_perm(b, a, 0x07060302u);
}

// Exact 3-way truncation split: x == hi + mid + lo bit-exactly in fp32.
struct Split3 { unsigned h, m, l; };
__device__ __forceinline__ Split3 split3(float x) {
    unsigned xu = __float_as_uint(x);
    float xh = __uint_as_float(xu & 0xFFFF0000u);
    float r  = x - xh;                        // exact
    unsigned ru = __float_as_uint(r);
    float xm = __uint_as_float(ru & 0xFFFF0000u);
    float r2 = r - xm;                        // exact, fits bf16
    return { xu, ru, __float_as_uint(r2) };
}

// 2-way split: hi + residual (packbf of r truncates -> the mid limb).
struct Split2 { unsigned h, r; };
__device__ __forceinline__ Split2 split2(float x) {
    unsigned xu = __float_as_uint(x);
    float xh = __uint_as_float(xu & 0xFFFF0000u);
    float rr = x - xh;                        // exact residual
    return { xu, __float_as_uint(rr) };
}

// Wave-specialized: 128-thread blocks; wave 0 = march (serial), wave 1 =
// tput scan (65 independent evals, pipelined) — same 16 rays, disjoint
// output bytes (xyz vs w), no inter-wave sync. 3 waves/SIMD resident:
// tput waves fill the march chain's stall cycles (TLP, not ILP).
// MFMA layouts (R6-verified): A[row=lane&15][k=quad*8+j],
// B[k=quad*8+j][col=lane&15], C/D col=lane&15 row=quad*4+reg.
// L1 hidden assignment H(t,q,r)=32*(t>>1)+8q+4*(t&1)+r -> in-lane C1->B2.
// Precision: march L2 = 3 products (m,h)(h,m)(h,h)  [~1e-6 perturbation];
//            tput  L2 = 2 products (h,m)(h,h)       [~5e-5 in w].
__global__ __launch_bounds__(128, 3) void sdf_mt_k(
    const float* __restrict__ rays,
    const float* __restrict__ W0,  const float* __restrict__ b0,
    const float* __restrict__ W1,  const float* __restrict__ b1,
    const float* __restrict__ W2,  const float* __restrict__ b2,
    const float* __restrict__ Wr0, const float* __restrict__ br0,
    const float* __restrict__ Wr1, const float* __restrict__ br1,
    float* __restrict__ out)
{
    const int lane = threadIdx.x & 63;
    const int kind = threadIdx.x >> 6;        // 0 = march, 1 = tput
    const int quad = lane >> 4;
    const int m    = lane & 15;
    const int rayBase = blockIdx.x * 16;

    // ---- per-lane ray (ray = rayBase + m, replicated over quads) ----
    const float* rp = rays + (rayBase + m) * 6;
    const float ox = rp[0], oy = rp[1], oz = rp[2];
    const float dx = rp[3], dy = rp[4], dz = rp[5];

    // ---- A2: W1^T hi/mid limbs in A-layout (16 frags = 64 regs) ----
    short8 A2h[2][4], A2m[2][4];
    #pragma unroll
    for (int h = 0; h < 2; ++h)
        #pragma unroll
        for (int t = 0; t < 4; ++t) {
            unsigned ph[4], pm[4];
            #pragma unroll
            for (int jp = 0; jp < 4; ++jp) {
                int k0 = 32 * h + quad * 8 + 2 * jp;
                int j2 = 16 * t + m;
                Split2 a = split2(W1[k0 * 64 + j2]);
                Split2 b = split2(W1[(k0 + 1) * 64 + j2]);
                ph[jp] = packbf(a.h, b.h);
                pm[jp] = packbf(a.r, b.r);     // trunc(residual) == mid limb
            }
            A2h[h][t] = mk_frag(ph[0], ph[1], ph[2], ph[3]);
            A2m[h][t] = mk_frag(pm[0], pm[1], pm[2], pm[3]);
        }

    // ---- A1: exact W0^T/b0 limbs, uniform per-quad K-slots (R9-verified) ----
    // quad<3: dwords (Wh,Wh)(Wh,Wm)(Wm,Wl)(0,0); quad3: (bh,bm)(bl,0)(0,0)(0,0)
    short8 A1[4];
    {
        const float* wbase = (quad == 0) ? W0 : (quad == 1) ? (W0 + 64)
                           : (quad == 2) ? (W0 + 128) : b0;
        #pragma unroll
        for (int t = 0; t < 4; ++t) {
            int j = 32 * (t >> 1) + 8 * (m >> 2) + 4 * (t & 1) + (m & 3);
            Split3 s = split3(wbase[j]);
            unsigned hh = packbf(s.h, s.h);
            unsigned hm = packbf(s.h, s.m);
            unsigned ml = packbf(s.m, s.l);
            unsigned l0 = packbf(s.l, 0u);
            bool is3 = (quad == 3);
            A1[t] = mk_frag(is3 ? hm : hh, is3 ? l0 : hm, is3 ? 0u : ml, 0u);
        }
    }

    // ---- b1 (C2 init) and W2 (L3), per-lane rows j2 = 16t+4q+r ----
    float4v b1v[4], w2v[4];
    #pragma unroll
    for (int t = 0; t < 4; ++t) {
        int base = 16 * t + 4 * quad;
        b1v[t] = (float4v){b1[base], b1[base + 1], b1[base + 2], b1[base + 3]};
        w2v[t] = (float4v){W2[base], W2[base + 1], W2[base + 2], W2[base + 3]};
    }
    const float b2s = b2[0];
    const float4v z4 = {0.f, 0.f, 0.f, 0.f};

    // ---- branchless exact B1 build (R9/R10-verified) ----
    auto buildB1 = [&](float px, float py, float pz) -> short8 {
        float c = (quad == 0) ? px : (quad == 1) ? py : pz;
        Split3 s = split3(c);
        unsigned d0 = packbf(s.h, s.m);
        unsigned d1 = packbf(s.l, s.h);
        unsigned d2 = packbf(s.m, s.h);
        if (quad == 3) { d0 = 0x3F803F80u; d1 = 0x00003F80u; d2 = 0u; }
        return mk_frag(d0, d1, d2, 0u);
    };

    // ---- shared front-end: pos -> exact L1 -> relu -> split2 pack ----
    auto front = [&](float px, float py, float pz, short8* BH, short8* BM) {
        short8 B1 = buildB1(px, py, pz);
        float4v C1[4];
        #pragma unroll
        for (int t = 0; t < 4; ++t)
            C1[t] = __builtin_amdgcn_mfma_f32_16x16x32_bf16(A1[t], B1, z4, 0, 0, 0);
        unsigned PH[4][2], PM[4][2];
        #pragma unroll
        for (int t = 0; t < 4; ++t) {
            float v0 = fmaxf(C1[t][0], 0.f), v1 = fmaxf(C1[t][1], 0.f);
            float v2 = fmaxf(C1[t][2], 0.f), v3 = fmaxf(C1[t][3], 0.f);
            unsigned u0 = __float_as_uint(v0), u1 = __float_as_uint(v1);
            unsigned u2 = __float_as_uint(v2), u3 = __float_as_uint(v3);
            PH[t][0] = packbf(u0, u1); PH[t][1] = packbf(u2, u3);
            float r0 = v0 - __uint_as_float(u0 & 0xFFFF0000u);
            float r1 = v1 - __uint_as_float(u1 & 0xFFFF0000u);
            float r2 = v2 - __uint_as_float(u2 & 0xFFFF0000u);
            float r3 = v3 - __uint_as_float(u3 & 0xFFFF0000u);
            PM[t][0] = packbf(__float_as_uint(r0), __float_as_uint(r1));
            PM[t][1] = packbf(__float_as_uint(r2), __float_as_uint(r3));
        }
        #pragma unroll
        for (int h = 0; h < 2; ++h) {
            BH[h] = mk_frag(PH[2 * h][0], PH[2 * h][1],
                            PH[2 * h + 1][0], PH[2 * h + 1][1]);
            BM[h] = mk_frag(PM[2 * h][0], PM[2 * h][1],
                            PM[2 * h + 1][0], PM[2 * h + 1][1]);
        }
    };

    // ---- L3: in-lane relu*W2, 2 cross-quad shuffles -> d at every lane ----
    auto l3 = [&](const float4v* C2) -> float {
        float q0 = 0.f, q1 = 0.f, q2 = 0.f, q3 = 0.f;
        #pragma unroll
        for (int t = 0; t < 4; ++t) {
            q0 = fmaf(fmaxf(C2[t][0], 0.f), w2v[t][0], q0);
            q1 = fmaf(fmaxf(C2[t][1], 0.f), w2v[t][1], q1);
            q2 = fmaf(fmaxf(C2[t][2], 0.f), w2v[t][2], q2);
            q3 = fmaf(fmaxf(C2[t][3], 0.f), w2v[t][3], q3);
        }
        float part = (q0 + q1) + (q2 + q3);
        part += __shfl_xor(part, 16, 64);
        part += __shfl_xor(part, 32, 64);
        return b2s + part;
    };

    if (kind == 0) {
        // =================== MARCH wave: 64 sequential evals ===============
        bool  hit = false;
        float cd  = 0.f;
        #pragma unroll 1
        for (int it = 0; it < MARCH_ITERS; ++it) {
            if (__all(hit)) break;
            short8 BH[2], BM[2];
            front(fmaf(dx, cd, ox), fmaf(dy, cd, oy), fmaf(dz, cd, oz), BH, BM);
            // L2: 3 products, small first: (m,h)(h,m)(h,h); 24 MFMAs
            float4v C2[4];
            #pragma unroll
            for (int t = 0; t < 4; ++t) C2[t] = b1v[t];
            #pragma unroll
            for (int h = 0; h < 2; ++h)
                #pragma unroll
                for (int t = 0; t < 4; ++t)
                    C2[t] = __builtin_amdgcn_mfma_f32_16x16x32_bf16(
                        A2m[h][t], BH[h], C2[t], 0, 0, 0);
            #pragma unroll
            for (int h = 0; h < 2; ++h)
                #pragma unroll
                for (int t = 0; t < 4; ++t)
                    C2[t] = __builtin_amdgcn_mfma_f32_16x16x32_bf16(
                        A2h[h][t], BM[h], C2[t], 0, 0, 0);
            #pragma unroll
            for (int h = 0; h < 2; ++h)
                #pragma unroll
                for (int t = 0; t < 4; ++t)
                    C2[t] = __builtin_amdgcn_mfma_f32_16x16x32_bf16(
                        A2h[h][t], BH[h], C2[t], 0, 0, 0);
            float dm = l3(C2);
            bool c = (dm < EPS_) && (cd >= 0.f) && (cd <= 1.f);
            hit = hit || c;
            if (!hit) cd += dm;
        }

        // ---- reflection net: quad q handles hidden j in [16q, 16q+16) ----
        const float px = fmaf(dx, cd, ox), py = fmaf(dy, cd, oy), pz = fmaf(dz, cd, oz);
        float r0 = 0.f, r1 = 0.f, r2 = 0.f;
        #pragma unroll 4
        for (int jj = 0; jj < 16; ++jj) {
            int j = quad * 16 + jj;
            float a = fmaf(px, Wr0[j],
                      fmaf(py, Wr0[64 + j],
                      fmaf(pz, Wr0[128 + j],
                      fmaf(dx, Wr0[192 + j],
                      fmaf(dy, Wr0[256 + j],
                      fmaf(dz, Wr0[320 + j], br0[j]))))));
            a = fmaxf(a, 0.f);
            r0 = fmaf(a, Wr1[j * 3 + 0], r0);
            r1 = fmaf(a, Wr1[j * 3 + 1], r1);
            r2 = fmaf(a, Wr1[j * 3 + 2], r2);
        }
        r0 += __shfl_xor(r0, 16, 64); r0 += __shfl_xor(r0, 32, 64);
        r1 += __shfl_xor(r1, 16, 64); r1 += __shfl_xor(r1, 32, 64);
        r2 += __shfl_xor(r2, 16, 64); r2 += __shfl_xor(r2, 32, 64);
        r0 = 1.f / (1.f + expf(-(r0 + br1[0])));
        r1 = 1.f / (1.f + expf(-(r1 + br1[1])));
        r2 = 1.f / (1.f + expf(-(r2 + br1[2])));
        if (!hit) { r0 = 0.f; r1 = 0.f; r2 = 0.f; }
        if (lane < 16) {
            float* op = out + (rayBase + lane) * 4;
            op[0] = r0; op[1] = r1; op[2] = r2;
        }
    } else {
        // =================== TPUT wave: 65 independent evals ===============
        // i=0 at origin (== reference curr_min0), then t = STEP*i.
        short8 BH[2], BM[2], BnH[2], BnM[2];
        front(ox, oy, oz, BH, BM);
        float cm = 3.4e38f;
        #pragma unroll 2
        for (int i = 0; i <= 64; ++i) {
            // L2: 2 products (h,m)(h,h); 16 MFMAs
            float4v C2[4];
            #pragma unroll
            for (int t = 0; t < 4; ++t) C2[t] = b1v[t];
            #pragma unroll
            for (int h = 0; h < 2; ++h)
                #pragma unroll
                for (int t = 0; t < 4; ++t)
                    C2[t] = __builtin_amdgcn_mfma_f32_16x16x32_bf16(
                        A2h[h][t], BM[h], C2[t], 0, 0, 0);
            #pragma unroll
            for (int h = 0; h < 2; ++h)
                #pragma unroll
                for (int t = 0; t < 4; ++t)
                    C2[t] = __builtin_amdgcn_mfma_f32_16x16x32_bf16(
                        A2h[h][t], BH[h], C2[t], 0, 0, 0);
            // next-eval front-end overlaps this L2/L3 (overrun at i=64 harmless)
            float tn = STEP_ * (float)(i + 1);
            front(fmaf(dx, tn, ox), fmaf(dy, tn, oy), fmaf(dz, tn, oz), BnH, BnM);
            float dt = l3(C2);
            cm = fminf(cm, dt);
            #pragma unroll
            for (int h = 0; h < 2; ++h) { BH[h] = BnH[h]; BM[h] = BnM[h]; }
        }
        if (lane < 16)
            out[(rayBase + lane) * 4 + 3] = cm;
    }
}

extern "C" void kernel_launch(void* const* d_in, const int* in_sizes, int n_in,
                              void* d_out, int out_size, void* d_ws, size_t ws_size,
                              hipStream_t stream) {
    const float* rays = (const float*)d_in[0];
    const float* W0   = (const float*)d_in[1];
    const float* b0   = (const float*)d_in[2];
    const float* W1   = (const float*)d_in[3];
    const float* b1   = (const float*)d_in[4];
    const float* W2   = (const float*)d_in[5];
    const float* b2   = (const float*)d_in[6];
    const float* Wr0  = (const float*)d_in[7];
    const float* br0  = (const float*)d_in[8];
    const float* Wr1  = (const float*)d_in[9];
    const float* br1  = (const float*)d_in[10];
    float* out = (float*)d_out;

    // 2048 blocks x 128 threads: per block, wave0 = march, wave1 = tput for
    // the same 16 rays. 4096 waves total; 3 waves/SIMD resident (reg cap 170).
    hipLaunchKernelGGL(sdf_mt_k, dim3(NRAYS / 16), dim3(128), 0, stream,
                       rays, W0, b0, W1, b1, W2, b2, Wr0, br0, Wr1, br1, out);
}

// Round 12
// 187.065 us; speedup vs baseline: 1.3404x; 1.0052x over previous
//
#include <hip/hip_runtime.h>
#include <math.h>

// Problem constants
#define NRAYS        32768
#define MARCH_ITERS  64
#define EPS_         1e-4f
#define STEP_        ((1.0f + 1.0f/64.0f) / 64.0f)   // exact in fp32

typedef __attribute__((ext_vector_type(8)))  short    short8;   // 8 bf16
typedef __attribute__((ext_vector_type(4)))  float    float4v;  // C/D frag
typedef __attribute__((ext_vector_type(4)))  unsigned uint4v;

__device__ __forceinline__ short8 mk_frag(unsigned p0, unsigned p1,
                                          unsigned p2, unsigned p3) {
    uint4v v = {p0, p1, p2, p3};
    return __builtin_bit_cast(short8, v);
}

// One v_perm_b32: low16 = trunc-bf16(a), high16 = trunc-bf16(b).
__device__ __forceinline__ unsigned packbf(unsigned a, unsigned b) {
    return __builtin_amdgcn_perm(b, a, 0x07060302u);
}

// Exact 3-way truncation split: x == hi + mid + lo bit-exactly in fp32.
struct Split3 { unsigned h, m, l; };
__device__ __forceinline__ Split3 split3(float x) {
    unsigned xu = __float_as_uint(x);
    float xh = __uint_as_float(xu & 0xFFFF0000u);
    float r  = x - xh;                        // exact
    unsigned ru = __float_as_uint(r);
    float xm = __uint_as_float(ru & 0xFFFF0000u);
    float r2 = r - xm;                        // exact, fits bf16
    return { xu, ru, __float_as_uint(r2) };
}

// 2-way split: hi + residual (packbf of r truncates -> the mid limb).
struct Split2 { unsigned h, r; };
__device__ __forceinline__ Split2 split2(float x) {
    unsigned xu = __float_as_uint(x);
    float xh = __uint_as_float(xu & 0xFFFF0000u);
    float rr = x - xh;                        // exact residual
    return { xu, __float_as_uint(rr) };
}

// Wave-specialized (R11 structure, R12 = branch-local weight builds to kill
// the spill): 128-thread blocks; wave 0 = march (serial), wave 1 = tput
// (65 independent evals, pipelined) — same 16 rays, disjoint output bytes.
// 3 waves/SIMD resident (__launch_bounds__(128,3), ~170-reg cap):
//   march-branch peak ~165 regs (A2h+A2m+A1+b1v+w2v+C2+temps)
//   tput-branch  peak ~130 regs (A2m never materialized there)
// MFMA layouts (R6-verified): A[row=lane&15][k=quad*8+j],
// B[k=quad*8+j][col=lane&15], C/D col=lane&15 row=quad*4+reg.
// L1 hidden assignment H(t,q,r)=32*(t>>1)+8q+4*(t&1)+r -> in-lane C1->B2.
// Precision: march L2 = 3 products (m,h)(h,m)(h,h); tput L2 = 2 products.
__global__ __launch_bounds__(128, 3) void sdf_mt2_k(
    const float* __restrict__ rays,
    const float* __restrict__ W0,  const float* __restrict__ b0,
    const float* __restrict__ W1,  const float* __restrict__ b1,
    const float* __restrict__ W2,  const float* __restrict__ b2,
    const float* __restrict__ Wr0, const float* __restrict__ br0,
    const float* __restrict__ Wr1, const float* __restrict__ br1,
    float* __restrict__ out)
{
    const int lane = threadIdx.x & 63;
    const int kind = threadIdx.x >> 6;        // 0 = march, 1 = tput
    const int quad = lane >> 4;
    const int m    = lane & 15;
    const int rayBase = blockIdx.x * 16;

    // ---- per-lane ray (ray = rayBase + m, replicated over quads) ----
    const float* rp = rays + (rayBase + m) * 6;
    const float ox = rp[0], oy = rp[1], oz = rp[2];
    const float dx = rp[3], dy = rp[4], dz = rp[5];

    // ---- A1: exact W0^T/b0 limbs, uniform per-quad K-slots (R9-verified) ----
    // quad<3: dwords (Wh,Wh)(Wh,Wm)(Wm,Wl)(0,0); quad3: (bh,bm)(bl,0)(0,0)(0,0)
    short8 A1[4];
    {
        const float* wbase = (quad == 0) ? W0 : (quad == 1) ? (W0 + 64)
                           : (quad == 2) ? (W0 + 128) : b0;
        #pragma unroll
        for (int t = 0; t < 4; ++t) {
            int j = 32 * (t >> 1) + 8 * (m >> 2) + 4 * (t & 1) + (m & 3);
            Split3 s = split3(wbase[j]);
            unsigned hh = packbf(s.h, s.h);
            unsigned hm = packbf(s.h, s.m);
            unsigned ml = packbf(s.m, s.l);
            unsigned l0 = packbf(s.l, 0u);
            bool is3 = (quad == 3);
            A1[t] = mk_frag(is3 ? hm : hh, is3 ? l0 : hm, is3 ? 0u : ml, 0u);
        }
    }

    // ---- b1 (C2 init) and W2 (L3), per-lane rows j2 = 16t+4q+r ----
    float4v b1v[4], w2v[4];
    #pragma unroll
    for (int t = 0; t < 4; ++t) {
        int base = 16 * t + 4 * quad;
        b1v[t] = (float4v){b1[base], b1[base + 1], b1[base + 2], b1[base + 3]};
        w2v[t] = (float4v){W2[base], W2[base + 1], W2[base + 2], W2[base + 3]};
    }
    const float b2s = b2[0];
    const float4v z4 = {0.f, 0.f, 0.f, 0.f};

    // ---- branchless exact B1 build (R9/R10-verified) ----
    auto buildB1 = [&](float px, float py, float pz) -> short8 {
        float c = (quad == 0) ? px : (quad == 1) ? py : pz;
        Split3 s = split3(c);
        unsigned d0 = packbf(s.h, s.m);
        unsigned d1 = packbf(s.l, s.h);
        unsigned d2 = packbf(s.m, s.h);
        if (quad == 3) { d0 = 0x3F803F80u; d1 = 0x00003F80u; d2 = 0u; }
        return mk_frag(d0, d1, d2, 0u);
    };

    // ---- shared front-end: pos -> exact L1 -> relu -> split2 pack ----
    auto front = [&](float px, float py, float pz, short8* BH, short8* BM) {
        short8 B1 = buildB1(px, py, pz);
        float4v C1[4];
        #pragma unroll
        for (int t = 0; t < 4; ++t)
            C1[t] = __builtin_amdgcn_mfma_f32_16x16x32_bf16(A1[t], B1, z4, 0, 0, 0);
        unsigned PH[4][2], PM[4][2];
        #pragma unroll
        for (int t = 0; t < 4; ++t) {
            float v0 = fmaxf(C1[t][0], 0.f), v1 = fmaxf(C1[t][1], 0.f);
            float v2 = fmaxf(C1[t][2], 0.f), v3 = fmaxf(C1[t][3], 0.f);
            unsigned u0 = __float_as_uint(v0), u1 = __float_as_uint(v1);
            unsigned u2 = __float_as_uint(v2), u3 = __float_as_uint(v3);
            PH[t][0] = packbf(u0, u1); PH[t][1] = packbf(u2, u3);
            float r0 = v0 - __uint_as_float(u0 & 0xFFFF0000u);
            float r1 = v1 - __uint_as_float(u1 & 0xFFFF0000u);
            float r2 = v2 - __uint_as_float(u2 & 0xFFFF0000u);
            float r3 = v3 - __uint_as_float(u3 & 0xFFFF0000u);
            PM[t][0] = packbf(__float_as_uint(r0), __float_as_uint(r1));
            PM[t][1] = packbf(__float_as_uint(r2), __float_as_uint(r3));
        }
        #pragma unroll
        for (int h = 0; h < 2; ++h) {
            BH[h] = mk_frag(PH[2 * h][0], PH[2 * h][1],
                            PH[2 * h + 1][0], PH[2 * h + 1][1]);
            BM[h] = mk_frag(PM[2 * h][0], PM[2 * h][1],
                            PM[2 * h + 1][0], PM[2 * h + 1][1]);
        }
    };

    // ---- L3: in-lane relu*W2, 2 cross-quad shuffles -> d at every lane ----
    auto l3 = [&](const float4v* C2) -> float {
        float q0 = 0.f, q1 = 0.f, q2 = 0.f, q3 = 0.f;
        #pragma unroll
        for (int t = 0; t < 4; ++t) {
            q0 = fmaf(fmaxf(C2[t][0], 0.f), w2v[t][0], q0);
            q1 = fmaf(fmaxf(C2[t][1], 0.f), w2v[t][1], q1);
            q2 = fmaf(fmaxf(C2[t][2], 0.f), w2v[t][2], q2);
            q3 = fmaf(fmaxf(C2[t][3], 0.f), w2v[t][3], q3);
        }
        float part = (q0 + q1) + (q2 + q3);
        part += __shfl_xor(part, 16, 64);
        part += __shfl_xor(part, 32, 64);
        return b2s + part;
    };

    if (kind == 0) {
        // =================== MARCH wave: 64 sequential evals ===============
        // Branch-local: BOTH W1 limbs (A2h + A2m), 32 frag-regs each.
        short8 A2h[2][4], A2m[2][4];
        #pragma unroll
        for (int h = 0; h < 2; ++h)
            #pragma unroll
            for (int t = 0; t < 4; ++t) {
                unsigned ph[4], pm[4];
                #pragma unroll
                for (int jp = 0; jp < 4; ++jp) {
                    int k0 = 32 * h + quad * 8 + 2 * jp;
                    int j2 = 16 * t + m;
                    Split2 a = split2(W1[k0 * 64 + j2]);
                    Split2 b = split2(W1[(k0 + 1) * 64 + j2]);
                    ph[jp] = packbf(a.h, b.h);
                    pm[jp] = packbf(a.r, b.r);   // trunc(residual) == mid limb
                }
                A2h[h][t] = mk_frag(ph[0], ph[1], ph[2], ph[3]);
                A2m[h][t] = mk_frag(pm[0], pm[1], pm[2], pm[3]);
            }

        bool  hit = false;
        float cd  = 0.f;
        #pragma unroll 1
        for (int it = 0; it < MARCH_ITERS; ++it) {
            if (__all(hit)) break;
            short8 BH[2], BM[2];
            front(fmaf(dx, cd, ox), fmaf(dy, cd, oy), fmaf(dz, cd, oz), BH, BM);
            // L2: 3 products, small first: (m,h)(h,m)(h,h); 24 MFMAs
            float4v C2[4];
            #pragma unroll
            for (int t = 0; t < 4; ++t) C2[t] = b1v[t];
            #pragma unroll
            for (int h = 0; h < 2; ++h)
                #pragma unroll
                for (int t = 0; t < 4; ++t)
                    C2[t] = __builtin_amdgcn_mfma_f32_16x16x32_bf16(
                        A2m[h][t], BH[h], C2[t], 0, 0, 0);
            #pragma unroll
            for (int h = 0; h < 2; ++h)
                #pragma unroll
                for (int t = 0; t < 4; ++t)
                    C2[t] = __builtin_amdgcn_mfma_f32_16x16x32_bf16(
                        A2h[h][t], BM[h], C2[t], 0, 0, 0);
            #pragma unroll
            for (int h = 0; h < 2; ++h)
                #pragma unroll
                for (int t = 0; t < 4; ++t)
                    C2[t] = __builtin_amdgcn_mfma_f32_16x16x32_bf16(
                        A2h[h][t], BH[h], C2[t], 0, 0, 0);
            float dm = l3(C2);
            bool c = (dm < EPS_) && (cd >= 0.f) && (cd <= 1.f);
            hit = hit || c;
            if (!hit) cd += dm;
        }

        // ---- reflection net: quad q handles hidden j in [16q, 16q+16) ----
        const float px = fmaf(dx, cd, ox), py = fmaf(dy, cd, oy), pz = fmaf(dz, cd, oz);
        float r0 = 0.f, r1 = 0.f, r2 = 0.f;
        #pragma unroll 4
        for (int jj = 0; jj < 16; ++jj) {
            int j = quad * 16 + jj;
            float a = fmaf(px, Wr0[j],
                      fmaf(py, Wr0[64 + j],
                      fmaf(pz, Wr0[128 + j],
                      fmaf(dx, Wr0[192 + j],
                      fmaf(dy, Wr0[256 + j],
                      fmaf(dz, Wr0[320 + j], br0[j]))))));
            a = fmaxf(a, 0.f);
            r0 = fmaf(a, Wr1[j * 3 + 0], r0);
            r1 = fmaf(a, Wr1[j * 3 + 1], r1);
            r2 = fmaf(a, Wr1[j * 3 + 2], r2);
        }
        r0 += __shfl_xor(r0, 16, 64); r0 += __shfl_xor(r0, 32, 64);
        r1 += __shfl_xor(r1, 16, 64); r1 += __shfl_xor(r1, 32, 64);
        r2 += __shfl_xor(r2, 16, 64); r2 += __shfl_xor(r2, 32, 64);
        r0 = 1.f / (1.f + expf(-(r0 + br1[0])));
        r1 = 1.f / (1.f + expf(-(r1 + br1[1])));
        r2 = 1.f / (1.f + expf(-(r2 + br1[2])));
        if (!hit) { r0 = 0.f; r1 = 0.f; r2 = 0.f; }
        if (lane < 16) {
            float* op = out + (rayBase + lane) * 4;
            op[0] = r0; op[1] = r1; op[2] = r2;
        }
    } else {
        // =================== TPUT wave: 65 independent evals ===============
        // Branch-local: ONLY the hi limb of W1 (A2h) — 32 frag-regs total.
        short8 A2h[2][4];
        #pragma unroll
        for (int h = 0; h < 2; ++h)
            #pragma unroll
            for (int t = 0; t < 4; ++t) {
                unsigned ph[4];
                #pragma unroll
                for (int jp = 0; jp < 4; ++jp) {
                    int k0 = 32 * h + quad * 8 + 2 * jp;
                    int j2 = 16 * t + m;
                    ph[jp] = packbf(__float_as_uint(W1[k0 * 64 + j2]),
                                    __float_as_uint(W1[(k0 + 1) * 64 + j2]));
                }
                A2h[h][t] = mk_frag(ph[0], ph[1], ph[2], ph[3]);
            }

        // i=0 at origin (== reference curr_min0), then t = STEP*i.
        short8 BH[2], BM[2], BnH[2], BnM[2];
        front(ox, oy, oz, BH, BM);
        float cm = 3.4e38f;
        #pragma unroll 2
        for (int i = 0; i <= 64; ++i) {
            // L2: 2 products (h,m)(h,h); 16 MFMAs
            float4v C2[4];
            #pragma unroll
            for (int t = 0; t < 4; ++t) C2[t] = b1v[t];
            #pragma unroll
            for (int h = 0; h < 2; ++h)
                #pragma unroll
                for (int t = 0; t < 4; ++t)
                    C2[t] = __builtin_amdgcn_mfma_f32_16x16x32_bf16(
                        A2h[h][t], BM[h], C2[t], 0, 0, 0);
            #pragma unroll
            for (int h = 0; h < 2; ++h)
                #pragma unroll
                for (int t = 0; t < 4; ++t)
                    C2[t] = __builtin_amdgcn_mfma_f32_16x16x32_bf16(
                        A2h[h][t], BH[h], C2[t], 0, 0, 0);
            // next-eval front-end overlaps this L2/L3 (overrun at i=64 harmless)
            float tn = STEP_ * (float)(i + 1);
            front(fmaf(dx, tn, ox), fmaf(dy, tn, oy), fmaf(dz, tn, oz), BnH, BnM);
            float dt = l3(C2);
            cm = fminf(cm, dt);
            #pragma unroll
            for (int h = 0; h < 2; ++h) { BH[h] = BnH[h]; BM[h] = BnM[h]; }
        }
        if (lane < 16)
            out[(rayBase + lane) * 4 + 3] = cm;
    }
}

extern "C" void kernel_launch(void* const* d_in, const int* in_sizes, int n_in,
                              void* d_out, int out_size, void* d_ws, size_t ws_size,
                              hipStream_t stream) {
    const float* rays = (const float*)d_in[0];
    const float* W0   = (const float*)d_in[1];
    const float* b0   = (const float*)d_in[2];
    const float* W1   = (const float*)d_in[3];
    const float* b1   = (const float*)d_in[4];
    const float* W2   = (const float*)d_in[5];
    const float* b2   = (const float*)d_in[6];
    const float* Wr0  = (const float*)d_in[7];
    const float* br0  = (const float*)d_in[8];
    const float* Wr1  = (const float*)d_in[9];
    const float* br1  = (const float*)d_in[10];
    float* out = (float*)d_out;

    // 2048 blocks x 128 threads: wave0 = march, wave1 = tput per 16 rays.
    // 4096 waves; 3 waves/SIMD resident, branch-local weights (no spill).
    hipLaunchKernelGGL(sdf_mt2_k, dim3(NRAYS / 16), dim3(128), 0, stream,
                       rays, W0, b0, W1, b1, W2, b2, Wr0, br0, Wr1, br1, out);
}